// Round 11
// baseline (228.597 us; speedup 1.0000x reference)
//
#include <hip/hip_runtime.h>
#include <hip/hip_bf16.h>

#define NV 8192
#define NF 4096
#define NM 12288
#define PFX 3
#define DOM 16
#define EMB 61
#define NN 36864
#define EE 262144
#define GG 8192
#define KK 16
#define OUT0 524288

typedef __hip_bfloat16 bf16;
__device__ __forceinline__ float b2f(bf16 x) { return __bfloat162float(x); }
__device__ __forceinline__ float lrelu(float x, float s) { return x > 0.f ? x : s * x; }
__device__ __forceinline__ float sigm(float x) { return 1.f / (1.f + expf(-x)); }
__device__ __forceinline__ float fexp(float x) { return __expf(fminf(x, 60.f)); }
__device__ __forceinline__ float LD(const void* p, int i, int f) {
  return f ? ((const float*)p)[i] : b2f(((const bf16*)p)[i]);
}
__device__ __forceinline__ void ST(void* p, int i, int f, float v) {
  if (f) ((float*)p)[i] = v; else ((bf16*)p)[i] = __float2bfloat16(v);
}
__device__ __forceinline__ int MK(const void* p, int i, int bytey) {
  return bytey ? (int)((const signed char*)p)[i] : ((const int*)p)[i];
}

// -------- dtype detector --------
__global__ void k_detect(const void* fn, const void* mask, int* flags) {
  if (threadIdx.x || blockIdx.x) return;
  int wild = 0;
  const bf16* h = (const bf16*)fn;
  for (int i = 0; i < 128; ++i) {
    float x = b2f(h[i]);
    float a = fabsf(x);
    if (a != a || a > 1e4f || (x != 0.f && a < 1e-8f)) ++wild;
  }
  flags[0] = (wild >= 8) ? 1 : 0;
  const int* mi = (const int*)mask;
  int bytey = 0;
  for (int i = 0; i < 64; ++i) {
    unsigned v = (unsigned)mi[i];
    if (v > 1u) bytey = 1;
  }
  flags[1] = bytey;
}

// -------- fused precompute: Wt (0-115), waS/waD (116), wqv/wkv (117), zero deg/cnt (118+) --
__global__ void k_precomp(const void* gv_wih, const void* gv_whh,
                          const void* gf_wih, const void* gf_whh,
                          const void* W4, const void* a4s, const void* a4d,
                          const void* wq, const void* wk, const void* ws,
                          float* Wt, float* waS, float* waD, float* wqv, float* wkv,
                          int* deg0, const int* flg) {
  int f = flg[0];
  int blk = blockIdx.x, tid = threadIdx.x;
  if (blk < 116) {
    int t = blk * 256 + tid;
    if (t < 2 * 77 * 192) {
      int dir = t / (77 * 192);
      int rem = t - dir * 77 * 192;
      int d = rem / 192, o = rem - d * 192;
      const void* wih = dir ? gf_wih : gv_wih;
      const void* whh = dir ? gf_whh : gv_whh;
      float v = 0.f;
      if (o < 183) v = (d < 16) ? LD(wih, o * 16 + d, f) : LD(whh, o * 61 + (d - 16), f);
      Wt[t] = v;
    }
  } else if (blk == 116) {
    int isD = tid >= 128;
    int u = tid & 127;
    int h = u >> 5, k = u & 31;
    const void* av = isD ? a4d : a4s;
    float acc = 0.f;
    for (int c = 0; c < 64; ++c) acc += LD(W4, k * 256 + h * 64 + c, f) * LD(av, h * 64 + c, f);
    (isD ? waD : waS)[h * 32 + k] = acc;
  } else if (blk == 117) {
    int h = tid >> 6, d = tid & 63;
    float q = 0.f, k = 0.f;
    for (int e = 0; e < 64; ++e) {
      q += LD(wq, h * 4096 + d * 64 + e, f) * LD(ws, h * 128 + e, f);
      k += LD(wk, h * 4096 + d * 64 + e, f) * LD(ws, h * 128 + 64 + e, f);
    }
    wqv[h * 64 + d] = q;
    wkv[h * 64 + d] = k;
  } else {
    int t = (blk - 118) * 256 + tid;
    if (t < 2 * NN) deg0[t] = 0;
  }
}

// ---------------- GRU v5: 32 rows/block, 512 threads (1-row tiles, 24 waves/CU) ----------
__global__ __launch_bounds__(512) void k_gru2(
    const void* v2f_msgs, const void* v2f_hid, const void* f2v_msgs, const void* f2v_hid,
    const void* gv_bih, const void* gv_bhh, const void* gf_bih, const void* gf_bhh,
    const float* Wt, float* hidcat, void* outv, const int* flg) {
  int f = flg[0];
  int blk = blockIdx.x;
  int dir = blk >= 384;
  int loc = dir ? blk - 384 : blk;
  int gr0 = loc * 32;
  const void* msgs = dir ? f2v_msgs : v2f_msgs;
  const void* hid = dir ? f2v_hid : v2f_hid;
  const void* bih = dir ? gf_bih : gv_bih;
  const void* bhh = dir ? gf_bhh : gv_bhh;
  const float* W = Wt + dir * 77 * 192;

  __shared__ float smem[7808];      // 31232 B
  float* F = smem;                  // [77][36], dead after accumulate
  float* G1 = smem;                 // [r*183 + o]
  float* G2 = smem + 32 * 183;      // [r*61 + j]

  int tid = threadIdx.x;
  for (int idx = tid; idx < 32 * 16; idx += 512) {
    int r = idx >> 4, d = idx & 15;
    F[d * 36 + r] = LD(msgs, (gr0 + r) * DOM + d, f);
  }
  for (int idx = tid; idx < 32 * 61; idx += 512) {
    int r = idx / 61, d = idx - r * 61;
    F[(16 + d) * 36 + r] = LD(hid, gr0 * 61 + idx, f);
  }
  __syncthreads();

  int og = tid & 15, rg = tid >> 4;  // og: 12 outputs, rg: 1 row (0..31)
  int o0 = og * 12;
  float accA[12], accB[12];
#pragma unroll
  for (int i = 0; i < 12; ++i) { accA[i] = 0.f; accB[i] = 0.f; }

#pragma unroll 4
  for (int d = 0; d < 16; ++d) {
    float fv = F[d * 36 + rg];
    const float4 w0 = *(const float4*)&W[d * 192 + o0];
    const float4 w1 = *(const float4*)&W[d * 192 + o0 + 4];
    const float4 w2 = *(const float4*)&W[d * 192 + o0 + 8];
    accA[0] += w0.x * fv; accA[1] += w0.y * fv; accA[2] += w0.z * fv; accA[3] += w0.w * fv;
    accA[4] += w1.x * fv; accA[5] += w1.y * fv; accA[6] += w1.z * fv; accA[7] += w1.w * fv;
    accA[8] += w2.x * fv; accA[9] += w2.y * fv; accA[10] += w2.z * fv; accA[11] += w2.w * fv;
  }
#pragma unroll 4
  for (int d = 16; d < 77; ++d) {
    float fv = F[d * 36 + rg];
    const float4 w0 = *(const float4*)&W[d * 192 + o0];
    const float4 w1 = *(const float4*)&W[d * 192 + o0 + 4];
    const float4 w2 = *(const float4*)&W[d * 192 + o0 + 8];
    accB[0] += w0.x * fv; accB[1] += w0.y * fv; accB[2] += w0.z * fv; accB[3] += w0.w * fv;
    accB[4] += w1.x * fv; accB[5] += w1.y * fv; accB[6] += w1.z * fv; accB[7] += w1.w * fv;
    accB[8] += w2.x * fv; accB[9] += w2.y * fv; accB[10] += w2.z * fv; accB[11] += w2.w * fv;
  }
  __syncthreads();  // F dead; G1/G2 may overwrite

#pragma unroll
  for (int k = 0; k < 12; ++k) {
    int o = o0 + k;
    if (o < 183) {
      float biv = LD(bih, o, f), bhv = LD(bhh, o, f);
      float gi = accA[k] + biv;
      float gh = accB[k] + bhv;
      if (o < 122) G1[rg * 183 + o] = gi + gh;
      else { G1[rg * 183 + o] = gi; G2[rg * 61 + (o - 122)] = gh; }
    }
  }
  __syncthreads();

  int j = tid & 63, rq = tid >> 6;  // rq 0..7, 4 rows each
  if (j < 61) {
    for (int rr = 0; rr < 4; ++rr) {
      int r = rq * 4 + rr;
      float gr = sigm(G1[r * 183 + j]);
      float gz = sigm(G1[r * 183 + 61 + j]);
      float gn = tanhf(G1[r * 183 + 122 + j] + gr * G2[r * 61 + j]);
      float hold = LD(hid, (gr0 + r) * 61 + j, f);
      float hn = (1.f - gz) * gn + gz * hold;
      int b = dir * NM + gr0 + r;
      hidcat[b * 61 + j] = hn;
      ST(outv, OUT0 + b * 61 + j, f, hn);
    }
  }
}

// ---------------- CSR build ----------------
__global__ void k_deg(const int* dst, int* deg) {
  int e = blockIdx.x * blockDim.x + threadIdx.x;
  if (e < EE) atomicAdd(&deg[dst[e]], 1);
}
__global__ void k_scan1(const int* deg, int* rowptr, int* bsum) {
  __shared__ int s[512];
  int g = blockIdx.x * 512 + threadIdx.x;
  int v = (g < NN) ? deg[g] : 0;
  s[threadIdx.x] = v;
  __syncthreads();
  for (int off = 1; off < 512; off <<= 1) {
    int t = (threadIdx.x >= off) ? s[threadIdx.x - off] : 0;
    __syncthreads();
    s[threadIdx.x] += t;
    __syncthreads();
  }
  if (g < NN) rowptr[g] = s[threadIdx.x] - v;
  if (threadIdx.x == 511) bsum[blockIdx.x] = s[511];
}
// scan of block sums + add to rowptr, single block of 512
__global__ void k_scan23(int* rowptr, const int* bsum, int nb) {
  __shared__ int ps[128];
  int tid = threadIdx.x;
  int v = 0;
  if (tid < 128) { v = (tid < nb) ? bsum[tid] : 0; ps[tid] = v; }
  __syncthreads();
  for (int off = 1; off < 128; off <<= 1) {
    int t = 0;
    if (tid < 128 && tid >= off) t = ps[tid - off];
    __syncthreads();
    if (tid < 128) ps[tid] += t;
    __syncthreads();
  }
  if (tid < 128) ps[tid] -= v;  // exclusive
  __syncthreads();
  for (int g = tid; g < NN; g += 512) rowptr[g] += ps[g >> 9];
  if (tid == 0) rowptr[NN] = EE;
}
__global__ void k_fill(const int* src, const int* dst, const int* rowptr, int* cnt, int* col) {
  int e = blockIdx.x * blockDim.x + threadIdx.x;
  if (e < EE) {
    int d = dst[e];
    int pos = rowptr[d] + atomicAdd(&cnt[d], 1);
    col[pos] = src[e];
  }
}

// ---------------- L1: fused assemble + x@W1 + coef ----------------
__global__ __launch_bounds__(256) void k_xl1(
    const void* vn_prefix, const int* vn_colors, const void* emb, const void* fn_embed,
    const void* msg_prefix, const float* hidcat, const void* W1, const void* a1s,
    const void* a1d, float* xl, float* a_s, float* a_d, const int* flg) {
  int f = flg[0];
  __shared__ float Wl[64 * 32];
  __shared__ float X[8][64];
  int tid = threadIdx.x;
  for (int t = tid; t < 2048; t += 256) Wl[t] = LD(W1, t, f);
  for (int t = tid; t < 512; t += 256) {
    int r = t >> 6, c = t & 63;
    int i = blockIdx.x * 8 + r;
    float v;
    if (i < NV) {
      v = (c < PFX) ? LD(vn_prefix, i * PFX + c, f) : LD(emb, vn_colors[i] * EMB + (c - PFX), f);
    } else if (i < NV + NF) {
      v = LD(fn_embed, (size_t)(i - NV) * 64 + c, f);
    } else {
      int jj = i - NV - NF;
      v = (c < PFX) ? LD(msg_prefix, jj * PFX + c, f) : hidcat[jj * EMB + (c - PFX)];
    }
    X[r][c] = v;
  }
  __syncthreads();
  int j = tid & 31, r = tid >> 5;
  int i = blockIdx.x * 8 + r;
  float acc = 0.f;
#pragma unroll
  for (int k = 0; k < 64; ++k) acc += X[r][k] * Wl[k * 32 + j];
  xl[(size_t)i * 32 + j] = acc;
  float sw = LD(a1s, j, f), dw = LD(a1d, j, f);
  float p = acc * sw, q = acc * dw;
#pragma unroll
  for (int off = 1; off < 8; off <<= 1) {
    p += __shfl_xor(p, off);
    q += __shfl_xor(q, off);
  }
  if ((j & 7) == 0) {
    a_s[(size_t)i * 4 + (j >> 3)] = p;
    a_d[(size_t)i * 4 + (j >> 3)] = q;
  }
}

// ---------------- GAT gather (max-free softmax): MODE0 = +next xl+coef; MODE1 = L3 -------
template <int MODE>
__global__ __launch_bounds__(256) void k_gather13(
    const int* rowptr, const int* col, const float* a_s, const float* a_d,
    const float* xl, const void* bias,
    const void* Wn, const void* asn_, const void* adn_,      // MODE0
    const float* waS, const float* waD,                       // MODE1
    float* xl_next, float* xout, float* as_out, float* ad_out, const int* flg) {
  int f = flg[0];
  __shared__ int colb[16][64];
  __shared__ float4 eb[16][64];
  __shared__ float Wn_l[32 * 32];
  __shared__ float an_s[32], an_d[32];
  __shared__ float Xr[16][33];
  __shared__ float SwaS[128], SwaD[128];
  int tid = threadIdx.x;
  if (MODE == 0) {
    for (int t = tid; t < 1024; t += 256) Wn_l[t] = LD(Wn, t, f);
    if (tid < 32) { an_s[tid] = LD(asn_, tid, f); an_d[tid] = LD(adn_, tid, f); }
  } else {
    if (tid < 128) { SwaS[tid] = waS[tid]; SwaD[tid] = waD[tid]; }
  }
  int g = tid >> 4, l = tid & 15;
  int i = blockIdx.x * 16 + g;
  int beg = rowptr[i], end = rowptr[i + 1];
  int deg = end - beg;
  float4 adv = *(const float4*)(a_d + (size_t)i * 4);
  float4 asv = *(const float4*)(a_s + (size_t)i * 4);
  float ad[4] = {adv.x, adv.y, adv.z, adv.w};
  float exS[4];
  {
    float asl[4] = {asv.x, asv.y, asv.z, asv.w};
#pragma unroll
    for (int h = 0; h < 4; ++h) exS[h] = fexp(lrelu(asl[h] + ad[h], 0.2f));
  }
  float den[4] = {0.f, 0.f, 0.f, 0.f};
  int c0 = l, c1 = l + 16;
  int h0 = l >> 3, h1 = 2 + (l >> 3);
  float acc0, acc1;

  if (deg <= 64) {
    // single edge pass: exp directly (no max), cache col + exp-scores in LDS
    for (int s = l; s < deg; s += 16) {
      int j = col[beg + s];
      colb[g][s] = j;
      float4 aj = *(const float4*)(a_s + (size_t)j * 4);
      float x0 = fexp(lrelu(aj.x + ad[0], 0.2f));
      float x1 = fexp(lrelu(aj.y + ad[1], 0.2f));
      float x2 = fexp(lrelu(aj.z + ad[2], 0.2f));
      float x3 = fexp(lrelu(aj.w + ad[3], 0.2f));
      eb[g][s] = make_float4(x0, x1, x2, x3);
      den[0] += x0; den[1] += x1; den[2] += x2; den[3] += x3;
    }
#pragma unroll
    for (int off = 1; off < 16; off <<= 1)
#pragma unroll
      for (int h = 0; h < 4; ++h) den[h] += __shfl_xor(den[h], off);
#pragma unroll
    for (int h = 0; h < 4; ++h) den[h] += exS[h];
    acc0 = exS[h0] * xl[(size_t)i * 32 + c0];
    acc1 = exS[h1] * xl[(size_t)i * 32 + c1];
#pragma unroll 2
    for (int s = 0; s < deg; ++s) {
      int j = colb[g][s];
      float4 e4 = eb[g][s];
      float w0 = h0 ? e4.y : e4.x;
      float w1 = (l >> 3) ? e4.w : e4.z;
      acc0 += w0 * xl[(size_t)j * 32 + c0];
      acc1 += w1 * xl[(size_t)j * 32 + c1];
    }
  } else {
    // generic path: recompute exp scores
    for (int s = l; s < deg; s += 16) {
      int j = col[beg + s];
      float4 aj = *(const float4*)(a_s + (size_t)j * 4);
      den[0] += fexp(lrelu(aj.x + ad[0], 0.2f));
      den[1] += fexp(lrelu(aj.y + ad[1], 0.2f));
      den[2] += fexp(lrelu(aj.z + ad[2], 0.2f));
      den[3] += fexp(lrelu(aj.w + ad[3], 0.2f));
    }
#pragma unroll
    for (int off = 1; off < 16; off <<= 1)
#pragma unroll
      for (int h = 0; h < 4; ++h) den[h] += __shfl_xor(den[h], off);
#pragma unroll
    for (int h = 0; h < 4; ++h) den[h] += exS[h];
    acc0 = exS[h0] * xl[(size_t)i * 32 + c0];
    acc1 = exS[h1] * xl[(size_t)i * 32 + c1];
    for (int s = 0; s < deg; ++s) {
      int j = col[beg + s];
      float e0 = fexp(lrelu(a_s[(size_t)j * 4 + h0] + ad[h0], 0.2f));
      float e1 = fexp(lrelu(a_s[(size_t)j * 4 + h1] + ad[h1], 0.2f));
      acc0 += e0 * xl[(size_t)j * 32 + c0];
      acc1 += e1 * xl[(size_t)j * 32 + c1];
    }
  }
  float v0 = lrelu(acc0 / den[h0] + LD(bias, c0, f), 0.01f);
  float v1 = lrelu(acc1 / den[h1] + LD(bias, c1, f), 0.01f);

  if (MODE == 0) {
    Xr[g][c0] = v0;
    Xr[g][c1] = v1;
    __syncthreads();
    float n0 = 0.f, n1 = 0.f;
#pragma unroll
    for (int k = 0; k < 32; ++k) {
      float xv = Xr[g][k];
      n0 += xv * Wn_l[k * 32 + c0];
      n1 += xv * Wn_l[k * 32 + c1];
    }
    xl_next[(size_t)i * 32 + c0] = n0;
    xl_next[(size_t)i * 32 + c1] = n1;
    float p0 = n0 * an_s[c0], q0 = n0 * an_d[c0];
    float p1 = n1 * an_s[c1], q1 = n1 * an_d[c1];
#pragma unroll
    for (int off = 1; off < 8; off <<= 1) {
      p0 += __shfl_xor(p0, off); q0 += __shfl_xor(q0, off);
      p1 += __shfl_xor(p1, off); q1 += __shfl_xor(q1, off);
    }
    if ((l & 7) == 0) {
      as_out[(size_t)i * 4 + h0] = p0;
      ad_out[(size_t)i * 4 + h0] = q0;
      as_out[(size_t)i * 4 + h1] = p1;
      ad_out[(size_t)i * 4 + h1] = q1;
    }
  } else {
    xout[(size_t)i * 32 + c0] = v0;
    xout[(size_t)i * 32 + c1] = v1;
    float pS[4], pD[4];
#pragma unroll
    for (int h = 0; h < 4; ++h) {
      pS[h] = v0 * SwaS[h * 32 + c0] + v1 * SwaS[h * 32 + c1];
      pD[h] = v0 * SwaD[h * 32 + c0] + v1 * SwaD[h * 32 + c1];
    }
#pragma unroll
    for (int off = 1; off < 16; off <<= 1)
#pragma unroll
      for (int h = 0; h < 4; ++h) { pS[h] += __shfl_xor(pS[h], off); pD[h] += __shfl_xor(pD[h], off); }
    if (l == 0) {
#pragma unroll
      for (int h = 0; h < 4; ++h) {
        as_out[(size_t)i * 4 + h] = pS[h];
        ad_out[(size_t)i * 4 + h] = pD[h];
      }
    }
  }
}

// ---------------- gather4 (max-free): only rows [NV, NV+NF) ----------------
__global__ __launch_bounds__(256) void k_gather4(const int* rowptr, const int* col,
                                                 const float* a_s, const float* a_d,
                                                 const float* x, float* agg) {
  __shared__ int colb[16][64];
  __shared__ float4 eb[16][64];
  int tid = threadIdx.x;
  int g = tid >> 4, l = tid & 15;
  int i = NV + blockIdx.x * 16 + g;
  int beg = rowptr[i], end = rowptr[i + 1];
  int deg = end - beg;
  float4 adv = *(const float4*)(a_d + (size_t)i * 4);
  float4 asv = *(const float4*)(a_s + (size_t)i * 4);
  float ad[4] = {adv.x, adv.y, adv.z, adv.w};
  float exS[4];
  {
    float asl[4] = {asv.x, asv.y, asv.z, asv.w};
#pragma unroll
    for (int h = 0; h < 4; ++h) exS[h] = fexp(lrelu(asl[h] + ad[h], 0.2f));
  }
  float den[4] = {0.f, 0.f, 0.f, 0.f};
  int k0 = l, k1 = l + 16;
  float acc[4][2];

  if (deg <= 64) {
    for (int s = l; s < deg; s += 16) {
      int j = col[beg + s];
      colb[g][s] = j;
      float4 aj = *(const float4*)(a_s + (size_t)j * 4);
      float x0 = fexp(lrelu(aj.x + ad[0], 0.2f));
      float x1 = fexp(lrelu(aj.y + ad[1], 0.2f));
      float x2 = fexp(lrelu(aj.z + ad[2], 0.2f));
      float x3 = fexp(lrelu(aj.w + ad[3], 0.2f));
      eb[g][s] = make_float4(x0, x1, x2, x3);
      den[0] += x0; den[1] += x1; den[2] += x2; den[3] += x3;
    }
#pragma unroll
    for (int off = 1; off < 16; off <<= 1)
#pragma unroll
      for (int h = 0; h < 4; ++h) den[h] += __shfl_xor(den[h], off);
    float xs0 = x[(size_t)i * 32 + k0], xs1 = x[(size_t)i * 32 + k1];
#pragma unroll
    for (int h = 0; h < 4; ++h) {
      den[h] += exS[h];
      acc[h][0] = exS[h] * xs0;
      acc[h][1] = exS[h] * xs1;
    }
#pragma unroll 2
    for (int s = 0; s < deg; ++s) {
      int j = colb[g][s];
      float4 e4 = eb[g][s];
      float xv0 = x[(size_t)j * 32 + k0], xv1 = x[(size_t)j * 32 + k1];
      acc[0][0] += e4.x * xv0; acc[0][1] += e4.x * xv1;
      acc[1][0] += e4.y * xv0; acc[1][1] += e4.y * xv1;
      acc[2][0] += e4.z * xv0; acc[2][1] += e4.z * xv1;
      acc[3][0] += e4.w * xv0; acc[3][1] += e4.w * xv1;
    }
  } else {
    for (int s = l; s < deg; s += 16) {
      int j = col[beg + s];
      float4 aj = *(const float4*)(a_s + (size_t)j * 4);
      den[0] += fexp(lrelu(aj.x + ad[0], 0.2f));
      den[1] += fexp(lrelu(aj.y + ad[1], 0.2f));
      den[2] += fexp(lrelu(aj.z + ad[2], 0.2f));
      den[3] += fexp(lrelu(aj.w + ad[3], 0.2f));
    }
#pragma unroll
    for (int off = 1; off < 16; off <<= 1)
#pragma unroll
      for (int h = 0; h < 4; ++h) den[h] += __shfl_xor(den[h], off);
    float xs0 = x[(size_t)i * 32 + k0], xs1 = x[(size_t)i * 32 + k1];
#pragma unroll
    for (int h = 0; h < 4; ++h) {
      den[h] += exS[h];
      acc[h][0] = exS[h] * xs0;
      acc[h][1] = exS[h] * xs1;
    }
    for (int s = 0; s < deg; ++s) {
      int j = col[beg + s];
      float4 aj = *(const float4*)(a_s + (size_t)j * 4);
      float e0 = fexp(lrelu(aj.x + ad[0], 0.2f));
      float e1 = fexp(lrelu(aj.y + ad[1], 0.2f));
      float e2 = fexp(lrelu(aj.z + ad[2], 0.2f));
      float e3 = fexp(lrelu(aj.w + ad[3], 0.2f));
      float xv0 = x[(size_t)j * 32 + k0], xv1 = x[(size_t)j * 32 + k1];
      acc[0][0] += e0 * xv0; acc[0][1] += e0 * xv1;
      acc[1][0] += e1 * xv0; acc[1][1] += e1 * xv1;
      acc[2][0] += e2 * xv0; acc[2][1] += e2 * xv1;
      acc[3][0] += e3 * xv0; acc[3][1] += e3 * xv1;
    }
  }
#pragma unroll
  for (int h = 0; h < 4; ++h) {
    agg[(size_t)i * 128 + h * 32 + k0] = acc[h][0] / den[h];
    agg[(size_t)i * 128 + h * 32 + k1] = acc[h][1] / den[h];
  }
}

// ---------------- L4 epilogue + fused qk: only rows [NV, NV+NF) ----------------
__global__ __launch_bounds__(256) void k_l4_out(const float* agg, const void* W4, const void* b4,
                                                const float* wqv, const float* wkv,
                                                float* qs, float* ks, const int* flg) {
  int f = flg[0];
  __shared__ float Wl[128 * 64];
  __shared__ float Al[64][132];
  __shared__ float Ql[256], Kl[256];
  int tid = threadIdx.x;
  int R0 = NV + blockIdx.x * 64;
  for (int t = tid; t < 128 * 64; t += 256) {
    int K = t >> 6, c = t & 63;
    int h = K >> 5, k = K & 31;
    Wl[t] = LD(W4, k * 256 + h * 64 + c, f);
  }
  {
    const float4* ag4 = (const float4*)(agg + (size_t)R0 * 128);
    for (int t = tid; t < 2048; t += 256) {
      int r = t >> 5, k4 = (t & 31) << 2;
      float4 v = ag4[t];
      *(float4*)&Al[r][k4] = v;
    }
  }
  if (tid < 256) { Ql[tid] = wqv[tid]; Kl[tid] = wkv[tid]; }
  __syncthreads();
  int c0 = (tid & 15) << 2, r0 = (tid >> 4) << 2;
  float acc[4][4];
#pragma unroll
  for (int j = 0; j < 4; ++j)
#pragma unroll
    for (int i = 0; i < 4; ++i) acc[j][i] = 0.f;
#pragma unroll 4
  for (int K = 0; K < 128; ++K) {
    float4 wv = *(const float4*)&Wl[K * 64 + c0];
    float a0 = Al[r0][K], a1 = Al[r0 + 1][K], a2 = Al[r0 + 2][K], a3 = Al[r0 + 3][K];
    acc[0][0] += a0 * wv.x; acc[0][1] += a0 * wv.y; acc[0][2] += a0 * wv.z; acc[0][3] += a0 * wv.w;
    acc[1][0] += a1 * wv.x; acc[1][1] += a1 * wv.y; acc[1][2] += a1 * wv.z; acc[1][3] += a1 * wv.w;
    acc[2][0] += a2 * wv.x; acc[2][1] += a2 * wv.y; acc[2][2] += a2 * wv.z; acc[2][3] += a2 * wv.w;
    acc[3][0] += a3 * wv.x; acc[3][1] += a3 * wv.y; acc[3][2] += a3 * wv.z; acc[3][3] += a3 * wv.w;
  }
  float bv[4];
#pragma unroll
  for (int i = 0; i < 4; ++i) bv[i] = LD(b4, c0 + i, f);
  float o[4][4];
#pragma unroll
  for (int j = 0; j < 4; ++j)
#pragma unroll
    for (int i = 0; i < 4; ++i) o[j][i] = lrelu(0.25f * acc[j][i] + bv[i], 0.01f);
  int nbase = R0 - NV + r0;
#pragma unroll
  for (int j = 0; j < 4; ++j) {
#pragma unroll
    for (int h = 0; h < 4; ++h) {
      float pq = o[j][0] * Ql[h * 64 + c0] + o[j][1] * Ql[h * 64 + c0 + 1] +
                 o[j][2] * Ql[h * 64 + c0 + 2] + o[j][3] * Ql[h * 64 + c0 + 3];
      float pk = o[j][0] * Kl[h * 64 + c0] + o[j][1] * Kl[h * 64 + c0 + 1] +
                 o[j][2] * Kl[h * 64 + c0 + 2] + o[j][3] * Kl[h * 64 + c0 + 3];
#pragma unroll
      for (int off = 1; off < 16; off <<= 1) {
        pq += __shfl_xor(pq, off);
        pk += __shfl_xor(pk, off);
      }
      if ((tid & 15) == 0) {
        qs[(size_t)(nbase + j) * 4 + h] = pq;
        ks[(size_t)(nbase + j) * 4 + h] = pk;
      }
    }
  }
}

__global__ void k_groups(const int* full, const void* mask, const int* tgt, const int* mult,
                         const float* qs, const float* ks, const void* att_b, void* outv,
                         const int* flg) {
  int f = flg[0], mbyte = flg[1];
  int g = blockIdx.x;
  int lane = threadIdx.x;
  int k = lane >> 2, h = lane & 3;
  int t = tgt[g];
  int idx = full[g * KK + k];
  int mk = MK(mask, g * KK + k, mbyte);
  float bh = LD(att_b, h, f);
  float qt = qs[t * 4 + h];
  float sc = sigm(qt + ks[idx * 4 + h] + bh);
  int is_tgt = (idx == t) && mk;
  int nbr = mk && !is_tgt;
  unsigned long long bal = __ballot(nbr != 0);
  int degm1 = (int)(__popcll(bal) >> 2);
  float ssum = nbr ? sc : 0.f;
  for (int off = 4; off < 64; off <<= 1) ssum += __shfl_xor(ssum, off);
  ssum /= (float)(degm1 > 1 ? degm1 : 1);
  float trg = sigm(qt + ks[t * 4 + h] + bh);
  float mxv = fmaxf(ssum, trg);
  float e0 = expf(ssum - mxv), e1 = expf(trg - mxv);
  float tw0 = e0 / (e0 + e1), tw1 = e1 / (e0 + e1);
  float msc = nbr ? sc : -1e30f;
  float m = msc;
  for (int off = 4; off < 64; off <<= 1) m = fmaxf(m, __shfl_xor(m, off));
  float ex = expf(msc - m);
  float den = ex;
  for (int off = 4; off < 64; off <<= 1) den += __shfl_xor(den, off);
  float w = ex / den * tw0 * (float)mult[g];
  float res = is_tgt ? tw1 : (nbr ? w : 0.f);
  if (degm1 == 0) res = 0.f;
  ST(outv, g * 64 + k * 4 + h, f, res);
}

extern "C" void kernel_launch(void* const* d_in, const int* in_sizes, int n_in,
                              void* d_out, int out_size, void* d_ws, size_t ws_size,
                              hipStream_t stream) {
  const int* edge = (const int*)d_in[0];
  const int* esrc = edge;
  const int* edst = edge + EE;
  const int* vn_colors = (const int*)d_in[1];
  const int* group_full = (const int*)d_in[2];
  const void* group_mask = d_in[3];
  const int* group_tgt = (const int*)d_in[4];
  const int* group_mult = (const int*)d_in[5];
  const void* vn_prefix = d_in[6];
  const void* fn_embed = d_in[7];
  const void* v2f_msgs = d_in[8];
  const void* v2f_hidden = d_in[9];
  const void* f2v_msgs = d_in[10];
  const void* f2v_hidden = d_in[11];
  const void* msg_prefix = d_in[12];
  const void* emb = d_in[13];
  const void* gv_wih = d_in[14];
  const void* gv_whh = d_in[15];
  const void* gv_bih = d_in[16];
  const void* gv_bhh = d_in[17];
  const void* gf_wih = d_in[18];
  const void* gf_whh = d_in[19];
  const void* gf_bih = d_in[20];
  const void* gf_bhh = d_in[21];
  const void* W1 = d_in[22];
  const void* a1s = d_in[23];
  const void* a1d = d_in[24];
  const void* b1 = d_in[25];
  const void* W2 = d_in[26];
  const void* a2s = d_in[27];
  const void* a2d = d_in[28];
  const void* b2 = d_in[29];
  const void* W3 = d_in[30];
  const void* a3s = d_in[31];
  const void* a3d = d_in[32];
  const void* b3 = d_in[33];
  const void* W4 = d_in[34];
  const void* a4s = d_in[35];
  const void* a4d = d_in[36];
  const void* b4 = d_in[37];
  const void* att_wq = d_in[38];
  const void* att_wk = d_in[39];
  const void* att_ws = d_in[40];
  const void* att_b = d_in[41];

  char* w = (char*)d_ws;
  size_t off = 0;
  auto carve = [&](size_t bytes) -> void* {
    void* p = w + off;
    off += (bytes + 255) & ~(size_t)255;
    return p;
  };
  int* flags = (int*)carve(16);
  float* Wt = (float*)carve((size_t)2 * 77 * 192 * 4);
  float* hidcat = (float*)carve((size_t)2 * NM * EMB * 4);
  float* xB = (float*)carve((size_t)NN * 64 * 4);
  float* scr = (float*)carve((size_t)NN * 128 * 4);
  float* a_sA = (float*)carve((size_t)NN * 4 * 4);
  float* a_dA = (float*)carve((size_t)NN * 4 * 4);
  float* a_sB = (float*)carve((size_t)NN * 4 * 4);
  float* a_dB = (float*)carve((size_t)NN * 4 * 4);
  int* deg = (int*)carve((size_t)2 * NN * 4);  // deg + cnt adjacent, zeroed in k_precomp
  int* cnt = deg + NN;
  int* rowptr = (int*)carve((size_t)(NN + 1) * 4);
  int* bsum = (int*)carve(128 * 4);
  int* col = (int*)carve((size_t)EE * 4);
  float* qs = (float*)carve((size_t)NF * 4 * 4);
  float* ks = (float*)carve((size_t)NF * 4 * 4);
  float* wqv = (float*)carve(256 * 4);
  float* wkv = (float*)carve(256 * 4);
  float* waS = (float*)carve(128 * 4);
  float* waD = (float*)carve(128 * 4);

  k_detect<<<1, 64, 0, stream>>>(fn_embed, group_mask, flags);
  k_precomp<<<118 + (2 * NN + 255) / 256, 256, 0, stream>>>(
      gv_wih, gv_whh, gf_wih, gf_whh, W4, a4s, a4d,
      att_wq, att_wk, att_ws, Wt, waS, waD, wqv, wkv, deg, flags);
  k_gru2<<<768, 512, 0, stream>>>(v2f_msgs, v2f_hidden, f2v_msgs, f2v_hidden,
                                  gv_bih, gv_bhh, gf_bih, gf_bhh, Wt, hidcat, d_out, flags);
  k_deg<<<EE / 256, 256, 0, stream>>>(edst, deg);
  k_scan1<<<72, 512, 0, stream>>>(deg, rowptr, bsum);
  k_scan23<<<1, 512, 0, stream>>>(rowptr, bsum, 72);
  k_fill<<<EE / 256, 256, 0, stream>>>(esrc, edst, rowptr, cnt, col);

  // L1: assemble + x@W1 + coef1 -> xl1 in scr, coefs in A
  k_xl1<<<NN / 8, 256, 0, stream>>>(vn_prefix, vn_colors, emb, fn_embed, msg_prefix,
                                    hidcat, W1, a1s, a1d, scr, a_sA, a_dA, flags);
  // gather L1 (+xl2+coef2): scr,A -> xB,B
  k_gather13<0><<<NN / 16, 256, 0, stream>>>(rowptr, col, a_sA, a_dA, scr, b1,
                                             W2, a2s, a2d, nullptr, nullptr,
                                             xB, nullptr, a_sB, a_dB, flags);
  // gather L2 (+xl3+coef3): xB,B -> scr,A
  k_gather13<0><<<NN / 16, 256, 0, stream>>>(rowptr, col, a_sB, a_dB, xB, b2,
                                             W3, a3s, a3d, nullptr, nullptr,
                                             scr, nullptr, a_sA, a_dA, flags);
  // gather L3 (+act out + coef4): scr,A -> xB (act), B (coef4)
  k_gather13<1><<<NN / 16, 256, 0, stream>>>(rowptr, col, a_sA, a_dA, scr, b3,
                                             nullptr, nullptr, nullptr, waS, waD,
                                             nullptr, xB, a_sB, a_dB, flags);
  // L4 (only fn rows): gather4 -> agg in scr; l4_out + fused qk -> qs/ks
  k_gather4<<<NF / 16, 256, 0, stream>>>(rowptr, col, a_sB, a_dB, xB, scr);
  k_l4_out<<<NF / 64, 256, 0, stream>>>(scr, W4, b4, wqv, wkv, qs, ks, flags);

  k_groups<<<GG, 64, 0, stream>>>(group_full, group_mask, group_tgt, group_mult,
                                  qs, ks, att_b, d_out, flags);
}

// Round 12
// 197.860 us; speedup vs baseline: 1.1553x; 1.1553x over previous
//
#include <hip/hip_runtime.h>
#include <hip/hip_bf16.h>

#define NV 8192
#define NF 4096
#define NM 12288
#define PFX 3
#define DOM 16
#define EMB 61
#define NN 36864
#define EE 262144
#define GG 8192
#define KK 16
#define OUT0 524288

typedef __hip_bfloat16 bf16;
__device__ __forceinline__ float b2f(bf16 x) { return __bfloat162float(x); }
__device__ __forceinline__ float lrelu(float x, float s) { return x > 0.f ? x : s * x; }
__device__ __forceinline__ float sigm(float x) { return 1.f / (1.f + expf(-x)); }
__device__ __forceinline__ float fexp(float x) { return __expf(fminf(x, 60.f)); }
__device__ __forceinline__ float LD(const void* p, int i, int f) {
  return f ? ((const float*)p)[i] : b2f(((const bf16*)p)[i]);
}
__device__ __forceinline__ void ST(void* p, int i, int f, float v) {
  if (f) ((float*)p)[i] = v; else ((bf16*)p)[i] = __float2bfloat16(v);
}
__device__ __forceinline__ int MK(const void* p, int i, int bytey) {
  return bytey ? (int)((const signed char*)p)[i] : ((const int*)p)[i];
}

// -------- dtype detector --------
__global__ void k_detect(const void* fn, const void* mask, int* flags) {
  if (threadIdx.x || blockIdx.x) return;
  int wild = 0;
  const bf16* h = (const bf16*)fn;
  for (int i = 0; i < 128; ++i) {
    float x = b2f(h[i]);
    float a = fabsf(x);
    if (a != a || a > 1e4f || (x != 0.f && a < 1e-8f)) ++wild;
  }
  flags[0] = (wild >= 8) ? 1 : 0;
  const int* mi = (const int*)mask;
  int bytey = 0;
  for (int i = 0; i < 64; ++i) {
    unsigned v = (unsigned)mi[i];
    if (v > 1u) bytey = 1;
  }
  flags[1] = bytey;
}

// -------- fused precompute: Wt (0-115), waS/waD (116), wqv/wkv (117), zero deg/cnt (118+) --
__global__ void k_precomp(const void* gv_wih, const void* gv_whh,
                          const void* gf_wih, const void* gf_whh,
                          const void* W4, const void* a4s, const void* a4d,
                          const void* wq, const void* wk, const void* ws,
                          float* Wt, float* waS, float* waD, float* wqv, float* wkv,
                          int* deg0, const int* flg) {
  int f = flg[0];
  int blk = blockIdx.x, tid = threadIdx.x;
  if (blk < 116) {
    int t = blk * 256 + tid;
    if (t < 2 * 77 * 192) {
      int dir = t / (77 * 192);
      int rem = t - dir * 77 * 192;
      int d = rem / 192, o = rem - d * 192;
      const void* wih = dir ? gf_wih : gv_wih;
      const void* whh = dir ? gf_whh : gv_whh;
      float v = 0.f;
      if (o < 183) v = (d < 16) ? LD(wih, o * 16 + d, f) : LD(whh, o * 61 + (d - 16), f);
      Wt[t] = v;
    }
  } else if (blk == 116) {
    int isD = tid >= 128;
    int u = tid & 127;
    int h = u >> 5, k = u & 31;
    const void* av = isD ? a4d : a4s;
    float acc = 0.f;
    for (int c = 0; c < 64; ++c) acc += LD(W4, k * 256 + h * 64 + c, f) * LD(av, h * 64 + c, f);
    (isD ? waD : waS)[h * 32 + k] = acc;
  } else if (blk == 117) {
    int h = tid >> 6, d = tid & 63;
    float q = 0.f, k = 0.f;
    for (int e = 0; e < 64; ++e) {
      q += LD(wq, h * 4096 + d * 64 + e, f) * LD(ws, h * 128 + e, f);
      k += LD(wk, h * 4096 + d * 64 + e, f) * LD(ws, h * 128 + 64 + e, f);
    }
    wqv[h * 64 + d] = q;
    wkv[h * 64 + d] = k;
  } else {
    int t = (blk - 118) * 256 + tid;
    if (t < 2 * NN) deg0[t] = 0;
  }
}

// ---------------- GRU v6: 32 rows/block, coalesced W loads (lane=output-chunk) ----------
// 4 waves/block; wave w -> rows w*8..w*8+7; lane l (<48) -> outputs 4l..4l+3.
// Per d: 1 coalesced float4 W load + 2 broadcast LDS F reads + 32 FMA.
__global__ __launch_bounds__(256) void k_gru2(
    const void* v2f_msgs, const void* v2f_hid, const void* f2v_msgs, const void* f2v_hid,
    const void* gv_bih, const void* gv_bhh, const void* gf_bih, const void* gf_bhh,
    const float* Wt, float* hidcat, void* outv, const int* flg) {
  int f = flg[0];
  int blk = blockIdx.x;
  int dir = blk >= 384;
  int loc = dir ? blk - 384 : blk;
  int gr0 = loc * 32;
  const void* msgs = dir ? f2v_msgs : v2f_msgs;
  const void* hid = dir ? f2v_hid : v2f_hid;
  const void* bih = dir ? gf_bih : gv_bih;
  const void* bhh = dir ? gf_bhh : gv_bhh;
  const float* W = Wt + dir * 77 * 192;

  __shared__ float GA[32 * 192];   // gi sums (padded o to 192); F[77][36] aliases front
  __shared__ float GB[32 * 192];   // gh sums
  float* F = GA;                   // 2772 floats, dead after accumulate

  int tid = threadIdx.x;
  for (int idx = tid; idx < 32 * 16; idx += 256) {
    int r = idx >> 4, d = idx & 15;
    F[d * 36 + r] = LD(msgs, (gr0 + r) * DOM + d, f);
  }
  for (int idx = tid; idx < 32 * 61; idx += 256) {
    int r = idx / 61, d = idx - r * 61;
    F[(16 + d) * 36 + r] = LD(hid, gr0 * 61 + idx, f);
  }
  __syncthreads();

  int lane = tid & 63, w = tid >> 6;
  int r0 = w * 8;
  int act = lane < 48;
  int o0 = act ? lane * 4 : 0;
  float accA[32], accB[32];   // [ri*4 + oi]
#pragma unroll
  for (int i = 0; i < 32; ++i) { accA[i] = 0.f; accB[i] = 0.f; }

#pragma unroll 4
  for (int d = 0; d < 16; ++d) {
    float4 wv = *(const float4*)&W[d * 192 + o0];
    float4 fa = *(const float4*)&F[d * 36 + r0];
    float4 fb = *(const float4*)&F[d * 36 + r0 + 4];
    float fr[8] = {fa.x, fa.y, fa.z, fa.w, fb.x, fb.y, fb.z, fb.w};
#pragma unroll
    for (int ri = 0; ri < 8; ++ri) {
      accA[ri * 4 + 0] += wv.x * fr[ri];
      accA[ri * 4 + 1] += wv.y * fr[ri];
      accA[ri * 4 + 2] += wv.z * fr[ri];
      accA[ri * 4 + 3] += wv.w * fr[ri];
    }
  }
#pragma unroll 4
  for (int d = 16; d < 77; ++d) {
    float4 wv = *(const float4*)&W[d * 192 + o0];
    float4 fa = *(const float4*)&F[d * 36 + r0];
    float4 fb = *(const float4*)&F[d * 36 + r0 + 4];
    float fr[8] = {fa.x, fa.y, fa.z, fa.w, fb.x, fb.y, fb.z, fb.w};
#pragma unroll
    for (int ri = 0; ri < 8; ++ri) {
      accB[ri * 4 + 0] += wv.x * fr[ri];
      accB[ri * 4 + 1] += wv.y * fr[ri];
      accB[ri * 4 + 2] += wv.z * fr[ri];
      accB[ri * 4 + 3] += wv.w * fr[ri];
    }
  }
  __syncthreads();  // F dead; GA/GB may now be written

  if (act) {
    float bi[4], bh[4];
#pragma unroll
    for (int c = 0; c < 4; ++c) {
      int o = o0 + c;
      bi[c] = (o < 183) ? LD(bih, o, f) : 0.f;
      bh[c] = (o < 183) ? LD(bhh, o, f) : 0.f;
    }
#pragma unroll
    for (int ri = 0; ri < 8; ++ri) {
      int r = r0 + ri;
      float4 ga, gb;
      ga.x = accA[ri * 4 + 0] + bi[0]; ga.y = accA[ri * 4 + 1] + bi[1];
      ga.z = accA[ri * 4 + 2] + bi[2]; ga.w = accA[ri * 4 + 3] + bi[3];
      gb.x = accB[ri * 4 + 0] + bh[0]; gb.y = accB[ri * 4 + 1] + bh[1];
      gb.z = accB[ri * 4 + 2] + bh[2]; gb.w = accB[ri * 4 + 3] + bh[3];
      *(float4*)&GA[r * 192 + o0] = ga;
      *(float4*)&GB[r * 192 + o0] = gb;
    }
  }
  __syncthreads();

  int j = tid & 63, rq = tid >> 6;
  if (j < 61) {
    for (int rr = 0; rr < 8; ++rr) {
      int r = rq * 8 + rr;
      float gr = sigm(GA[r * 192 + j] + GB[r * 192 + j]);
      float gz = sigm(GA[r * 192 + 61 + j] + GB[r * 192 + 61 + j]);
      float gn = tanhf(GA[r * 192 + 122 + j] + gr * GB[r * 192 + 122 + j]);
      float hold = LD(hid, (gr0 + r) * 61 + j, f);
      float hn = (1.f - gz) * gn + gz * hold;
      int b = dir * NM + gr0 + r;
      hidcat[b * 61 + j] = hn;
      ST(outv, OUT0 + b * 61 + j, f, hn);
    }
  }
}

// ---------------- CSR build ----------------
__global__ void k_deg(const int* dst, int* deg) {
  int e = blockIdx.x * blockDim.x + threadIdx.x;
  if (e < EE) atomicAdd(&deg[dst[e]], 1);
}
__global__ void k_scan1(const int* deg, int* rowptr, int* bsum) {
  __shared__ int s[512];
  int g = blockIdx.x * 512 + threadIdx.x;
  int v = (g < NN) ? deg[g] : 0;
  s[threadIdx.x] = v;
  __syncthreads();
  for (int off = 1; off < 512; off <<= 1) {
    int t = (threadIdx.x >= off) ? s[threadIdx.x - off] : 0;
    __syncthreads();
    s[threadIdx.x] += t;
    __syncthreads();
  }
  if (g < NN) rowptr[g] = s[threadIdx.x] - v;
  if (threadIdx.x == 511) bsum[blockIdx.x] = s[511];
}
__global__ void k_scan23(int* rowptr, const int* bsum, int nb) {
  __shared__ int ps[128];
  int tid = threadIdx.x;
  int v = 0;
  if (tid < 128) { v = (tid < nb) ? bsum[tid] : 0; ps[tid] = v; }
  __syncthreads();
  for (int off = 1; off < 128; off <<= 1) {
    int t = 0;
    if (tid < 128 && tid >= off) t = ps[tid - off];
    __syncthreads();
    if (tid < 128) ps[tid] += t;
    __syncthreads();
  }
  if (tid < 128) ps[tid] -= v;  // exclusive
  __syncthreads();
  for (int g = tid; g < NN; g += 512) rowptr[g] += ps[g >> 9];
  if (tid == 0) rowptr[NN] = EE;
}
__global__ void k_fill(const int* src, const int* dst, const int* rowptr, int* cnt, int* col) {
  int e = blockIdx.x * blockDim.x + threadIdx.x;
  if (e < EE) {
    int d = dst[e];
    int pos = rowptr[d] + atomicAdd(&cnt[d], 1);
    col[pos] = src[e];
  }
}

// ---------------- L1: fused assemble + x@W1 + coef ----------------
__global__ __launch_bounds__(256) void k_xl1(
    const void* vn_prefix, const int* vn_colors, const void* emb, const void* fn_embed,
    const void* msg_prefix, const float* hidcat, const void* W1, const void* a1s,
    const void* a1d, float* xl, float* a_s, float* a_d, const int* flg) {
  int f = flg[0];
  __shared__ float Wl[64 * 32];
  __shared__ float X[8][64];
  int tid = threadIdx.x;
  for (int t = tid; t < 2048; t += 256) Wl[t] = LD(W1, t, f);
  for (int t = tid; t < 512; t += 256) {
    int r = t >> 6, c = t & 63;
    int i = blockIdx.x * 8 + r;
    float v;
    if (i < NV) {
      v = (c < PFX) ? LD(vn_prefix, i * PFX + c, f) : LD(emb, vn_colors[i] * EMB + (c - PFX), f);
    } else if (i < NV + NF) {
      v = LD(fn_embed, (size_t)(i - NV) * 64 + c, f);
    } else {
      int jj = i - NV - NF;
      v = (c < PFX) ? LD(msg_prefix, jj * PFX + c, f) : hidcat[jj * EMB + (c - PFX)];
    }
    X[r][c] = v;
  }
  __syncthreads();
  int j = tid & 31, r = tid >> 5;
  int i = blockIdx.x * 8 + r;
  float acc = 0.f;
#pragma unroll
  for (int k = 0; k < 64; ++k) acc += X[r][k] * Wl[k * 32 + j];
  xl[(size_t)i * 32 + j] = acc;
  float sw = LD(a1s, j, f), dw = LD(a1d, j, f);
  float p = acc * sw, q = acc * dw;
#pragma unroll
  for (int off = 1; off < 8; off <<= 1) {
    p += __shfl_xor(p, off);
    q += __shfl_xor(q, off);
  }
  if ((j & 7) == 0) {
    a_s[(size_t)i * 4 + (j >> 3)] = p;
    a_d[(size_t)i * 4 + (j >> 3)] = q;
  }
}

// ---------------- GAT gather (max-free softmax): MODE0 = +next xl+coef; MODE1 = L3 -------
template <int MODE>
__global__ __launch_bounds__(256) void k_gather13(
    const int* rowptr, const int* col, const float* a_s, const float* a_d,
    const float* xl, const void* bias,
    const void* Wn, const void* asn_, const void* adn_,      // MODE0
    const float* waS, const float* waD,                       // MODE1
    float* xl_next, float* xout, float* as_out, float* ad_out, const int* flg) {
  int f = flg[0];
  __shared__ int colb[16][64];
  __shared__ float4 eb[16][64];
  __shared__ float Wn_l[32 * 32];
  __shared__ float an_s[32], an_d[32];
  __shared__ float Xr[16][33];
  __shared__ float SwaS[128], SwaD[128];
  int tid = threadIdx.x;
  if (MODE == 0) {
    for (int t = tid; t < 1024; t += 256) Wn_l[t] = LD(Wn, t, f);
    if (tid < 32) { an_s[tid] = LD(asn_, tid, f); an_d[tid] = LD(adn_, tid, f); }
  } else {
    if (tid < 128) { SwaS[tid] = waS[tid]; SwaD[tid] = waD[tid]; }
  }
  int g = tid >> 4, l = tid & 15;
  int i = blockIdx.x * 16 + g;
  int beg = rowptr[i], end = rowptr[i + 1];
  int deg = end - beg;
  float4 adv = *(const float4*)(a_d + (size_t)i * 4);
  float4 asv = *(const float4*)(a_s + (size_t)i * 4);
  float ad[4] = {adv.x, adv.y, adv.z, adv.w};
  float exS[4];
  {
    float asl[4] = {asv.x, asv.y, asv.z, asv.w};
#pragma unroll
    for (int h = 0; h < 4; ++h) exS[h] = fexp(lrelu(asl[h] + ad[h], 0.2f));
  }
  float den[4] = {0.f, 0.f, 0.f, 0.f};
  int c0 = l, c1 = l + 16;
  int h0 = l >> 3, h1 = 2 + (l >> 3);
  float acc0, acc1;

  if (deg <= 64) {
    for (int s = l; s < deg; s += 16) {
      int j = col[beg + s];
      colb[g][s] = j;
      float4 aj = *(const float4*)(a_s + (size_t)j * 4);
      float x0 = fexp(lrelu(aj.x + ad[0], 0.2f));
      float x1 = fexp(lrelu(aj.y + ad[1], 0.2f));
      float x2 = fexp(lrelu(aj.z + ad[2], 0.2f));
      float x3 = fexp(lrelu(aj.w + ad[3], 0.2f));
      eb[g][s] = make_float4(x0, x1, x2, x3);
      den[0] += x0; den[1] += x1; den[2] += x2; den[3] += x3;
    }
#pragma unroll
    for (int off = 1; off < 16; off <<= 1)
#pragma unroll
      for (int h = 0; h < 4; ++h) den[h] += __shfl_xor(den[h], off);
#pragma unroll
    for (int h = 0; h < 4; ++h) den[h] += exS[h];
    acc0 = exS[h0] * xl[(size_t)i * 32 + c0];
    acc1 = exS[h1] * xl[(size_t)i * 32 + c1];
#pragma unroll 2
    for (int s = 0; s < deg; ++s) {
      int j = colb[g][s];
      float4 e4 = eb[g][s];
      float w0 = h0 ? e4.y : e4.x;
      float w1 = (l >> 3) ? e4.w : e4.z;
      acc0 += w0 * xl[(size_t)j * 32 + c0];
      acc1 += w1 * xl[(size_t)j * 32 + c1];
    }
  } else {
    for (int s = l; s < deg; s += 16) {
      int j = col[beg + s];
      float4 aj = *(const float4*)(a_s + (size_t)j * 4);
      den[0] += fexp(lrelu(aj.x + ad[0], 0.2f));
      den[1] += fexp(lrelu(aj.y + ad[1], 0.2f));
      den[2] += fexp(lrelu(aj.z + ad[2], 0.2f));
      den[3] += fexp(lrelu(aj.w + ad[3], 0.2f));
    }
#pragma unroll
    for (int off = 1; off < 16; off <<= 1)
#pragma unroll
      for (int h = 0; h < 4; ++h) den[h] += __shfl_xor(den[h], off);
#pragma unroll
    for (int h = 0; h < 4; ++h) den[h] += exS[h];
    acc0 = exS[h0] * xl[(size_t)i * 32 + c0];
    acc1 = exS[h1] * xl[(size_t)i * 32 + c1];
    for (int s = 0; s < deg; ++s) {
      int j = col[beg + s];
      float e0 = fexp(lrelu(a_s[(size_t)j * 4 + h0] + ad[h0], 0.2f));
      float e1 = fexp(lrelu(a_s[(size_t)j * 4 + h1] + ad[h1], 0.2f));
      acc0 += e0 * xl[(size_t)j * 32 + c0];
      acc1 += e1 * xl[(size_t)j * 32 + c1];
    }
  }
  float v0 = lrelu(acc0 / den[h0] + LD(bias, c0, f), 0.01f);
  float v1 = lrelu(acc1 / den[h1] + LD(bias, c1, f), 0.01f);

  if (MODE == 0) {
    Xr[g][c0] = v0;
    Xr[g][c1] = v1;
    __syncthreads();
    float n0 = 0.f, n1 = 0.f;
#pragma unroll
    for (int k = 0; k < 32; ++k) {
      float xv = Xr[g][k];
      n0 += xv * Wn_l[k * 32 + c0];
      n1 += xv * Wn_l[k * 32 + c1];
    }
    xl_next[(size_t)i * 32 + c0] = n0;
    xl_next[(size_t)i * 32 + c1] = n1;
    float p0 = n0 * an_s[c0], q0 = n0 * an_d[c0];
    float p1 = n1 * an_s[c1], q1 = n1 * an_d[c1];
#pragma unroll
    for (int off = 1; off < 8; off <<= 1) {
      p0 += __shfl_xor(p0, off); q0 += __shfl_xor(q0, off);
      p1 += __shfl_xor(p1, off); q1 += __shfl_xor(q1, off);
    }
    if ((l & 7) == 0) {
      as_out[(size_t)i * 4 + h0] = p0;
      ad_out[(size_t)i * 4 + h0] = q0;
      as_out[(size_t)i * 4 + h1] = p1;
      ad_out[(size_t)i * 4 + h1] = q1;
    }
  } else {
    xout[(size_t)i * 32 + c0] = v0;
    xout[(size_t)i * 32 + c1] = v1;
    float pS[4], pD[4];
#pragma unroll
    for (int h = 0; h < 4; ++h) {
      pS[h] = v0 * SwaS[h * 32 + c0] + v1 * SwaS[h * 32 + c1];
      pD[h] = v0 * SwaD[h * 32 + c0] + v1 * SwaD[h * 32 + c1];
    }
#pragma unroll
    for (int off = 1; off < 16; off <<= 1)
#pragma unroll
      for (int h = 0; h < 4; ++h) { pS[h] += __shfl_xor(pS[h], off); pD[h] += __shfl_xor(pD[h], off); }
    if (l == 0) {
#pragma unroll
      for (int h = 0; h < 4; ++h) {
        as_out[(size_t)i * 4 + h] = pS[h];
        ad_out[(size_t)i * 4 + h] = pD[h];
      }
    }
  }
}

// ---------------- gather4 (max-free): only rows [NV, NV+NF) ----------------
__global__ __launch_bounds__(256) void k_gather4(const int* rowptr, const int* col,
                                                 const float* a_s, const float* a_d,
                                                 const float* x, float* agg) {
  __shared__ int colb[16][64];
  __shared__ float4 eb[16][64];
  int tid = threadIdx.x;
  int g = tid >> 4, l = tid & 15;
  int i = NV + blockIdx.x * 16 + g;
  int beg = rowptr[i], end = rowptr[i + 1];
  int deg = end - beg;
  float4 adv = *(const float4*)(a_d + (size_t)i * 4);
  float4 asv = *(const float4*)(a_s + (size_t)i * 4);
  float ad[4] = {adv.x, adv.y, adv.z, adv.w};
  float exS[4];
  {
    float asl[4] = {asv.x, asv.y, asv.z, asv.w};
#pragma unroll
    for (int h = 0; h < 4; ++h) exS[h] = fexp(lrelu(asl[h] + ad[h], 0.2f));
  }
  float den[4] = {0.f, 0.f, 0.f, 0.f};
  int k0 = l, k1 = l + 16;
  float acc[4][2];

  if (deg <= 64) {
    for (int s = l; s < deg; s += 16) {
      int j = col[beg + s];
      colb[g][s] = j;
      float4 aj = *(const float4*)(a_s + (size_t)j * 4);
      float x0 = fexp(lrelu(aj.x + ad[0], 0.2f));
      float x1 = fexp(lrelu(aj.y + ad[1], 0.2f));
      float x2 = fexp(lrelu(aj.z + ad[2], 0.2f));
      float x3 = fexp(lrelu(aj.w + ad[3], 0.2f));
      eb[g][s] = make_float4(x0, x1, x2, x3);
      den[0] += x0; den[1] += x1; den[2] += x2; den[3] += x3;
    }
#pragma unroll
    for (int off = 1; off < 16; off <<= 1)
#pragma unroll
      for (int h = 0; h < 4; ++h) den[h] += __shfl_xor(den[h], off);
    float xs0 = x[(size_t)i * 32 + k0], xs1 = x[(size_t)i * 32 + k1];
#pragma unroll
    for (int h = 0; h < 4; ++h) {
      den[h] += exS[h];
      acc[h][0] = exS[h] * xs0;
      acc[h][1] = exS[h] * xs1;
    }
#pragma unroll 2
    for (int s = 0; s < deg; ++s) {
      int j = colb[g][s];
      float4 e4 = eb[g][s];
      float xv0 = x[(size_t)j * 32 + k0], xv1 = x[(size_t)j * 32 + k1];
      acc[0][0] += e4.x * xv0; acc[0][1] += e4.x * xv1;
      acc[1][0] += e4.y * xv0; acc[1][1] += e4.y * xv1;
      acc[2][0] += e4.z * xv0; acc[2][1] += e4.z * xv1;
      acc[3][0] += e4.w * xv0; acc[3][1] += e4.w * xv1;
    }
  } else {
    for (int s = l; s < deg; s += 16) {
      int j = col[beg + s];
      float4 aj = *(const float4*)(a_s + (size_t)j * 4);
      den[0] += fexp(lrelu(aj.x + ad[0], 0.2f));
      den[1] += fexp(lrelu(aj.y + ad[1], 0.2f));
      den[2] += fexp(lrelu(aj.z + ad[2], 0.2f));
      den[3] += fexp(lrelu(aj.w + ad[3], 0.2f));
    }
#pragma unroll
    for (int off = 1; off < 16; off <<= 1)
#pragma unroll
      for (int h = 0; h < 4; ++h) den[h] += __shfl_xor(den[h], off);
    float xs0 = x[(size_t)i * 32 + k0], xs1 = x[(size_t)i * 32 + k1];
#pragma unroll
    for (int h = 0; h < 4; ++h) {
      den[h] += exS[h];
      acc[h][0] = exS[h] * xs0;
      acc[h][1] = exS[h] * xs1;
    }
    for (int s = 0; s < deg; ++s) {
      int j = col[beg + s];
      float4 aj = *(const float4*)(a_s + (size_t)j * 4);
      float e0 = fexp(lrelu(aj.x + ad[0], 0.2f));
      float e1 = fexp(lrelu(aj.y + ad[1], 0.2f));
      float e2 = fexp(lrelu(aj.z + ad[2], 0.2f));
      float e3 = fexp(lrelu(aj.w + ad[3], 0.2f));
      float xv0 = x[(size_t)j * 32 + k0], xv1 = x[(size_t)j * 32 + k1];
      acc[0][0] += e0 * xv0; acc[0][1] += e0 * xv1;
      acc[1][0] += e1 * xv0; acc[1][1] += e1 * xv1;
      acc[2][0] += e2 * xv0; acc[2][1] += e2 * xv1;
      acc[3][0] += e3 * xv0; acc[3][1] += e3 * xv1;
    }
  }
#pragma unroll
  for (int h = 0; h < 4; ++h) {
    agg[(size_t)i * 128 + h * 32 + k0] = acc[h][0] / den[h];
    agg[(size_t)i * 128 + h * 32 + k1] = acc[h][1] / den[h];
  }
}

// ---------------- L4 epilogue + fused qk: only rows [NV, NV+NF) ----------------
__global__ __launch_bounds__(256) void k_l4_out(const float* agg, const void* W4, const void* b4,
                                                const float* wqv, const float* wkv,
                                                float* qs, float* ks, const int* flg) {
  int f = flg[0];
  __shared__ float Wl[128 * 64];
  __shared__ float Al[64][132];
  __shared__ float Ql[256], Kl[256];
  int tid = threadIdx.x;
  int R0 = NV + blockIdx.x * 64;
  for (int t = tid; t < 128 * 64; t += 256) {
    int K = t >> 6, c = t & 63;
    int h = K >> 5, k = K & 31;
    Wl[t] = LD(W4, k * 256 + h * 64 + c, f);
  }
  {
    const float4* ag4 = (const float4*)(agg + (size_t)R0 * 128);
    for (int t = tid; t < 2048; t += 256) {
      int r = t >> 5, k4 = (t & 31) << 2;
      float4 v = ag4[t];
      *(float4*)&Al[r][k4] = v;
    }
  }
  if (tid < 256) { Ql[tid] = wqv[tid]; Kl[tid] = wkv[tid]; }
  __syncthreads();
  int c0 = (tid & 15) << 2, r0 = (tid >> 4) << 2;
  float acc[4][4];
#pragma unroll
  for (int j = 0; j < 4; ++j)
#pragma unroll
    for (int i = 0; i < 4; ++i) acc[j][i] = 0.f;
#pragma unroll 4
  for (int K = 0; K < 128; ++K) {
    float4 wv = *(const float4*)&Wl[K * 64 + c0];
    float a0 = Al[r0][K], a1 = Al[r0 + 1][K], a2 = Al[r0 + 2][K], a3 = Al[r0 + 3][K];
    acc[0][0] += a0 * wv.x; acc[0][1] += a0 * wv.y; acc[0][2] += a0 * wv.z; acc[0][3] += a0 * wv.w;
    acc[1][0] += a1 * wv.x; acc[1][1] += a1 * wv.y; acc[1][2] += a1 * wv.z; acc[1][3] += a1 * wv.w;
    acc[2][0] += a2 * wv.x; acc[2][1] += a2 * wv.y; acc[2][2] += a2 * wv.z; acc[2][3] += a2 * wv.w;
    acc[3][0] += a3 * wv.x; acc[3][1] += a3 * wv.y; acc[3][2] += a3 * wv.z; acc[3][3] += a3 * wv.w;
  }
  float bv[4];
#pragma unroll
  for (int i = 0; i < 4; ++i) bv[i] = LD(b4, c0 + i, f);
  float o[4][4];
#pragma unroll
  for (int j = 0; j < 4; ++j)
#pragma unroll
    for (int i = 0; i < 4; ++i) o[j][i] = lrelu(0.25f * acc[j][i] + bv[i], 0.01f);
  int nbase = R0 - NV + r0;
#pragma unroll
  for (int j = 0; j < 4; ++j) {
#pragma unroll
    for (int h = 0; h < 4; ++h) {
      float pq = o[j][0] * Ql[h * 64 + c0] + o[j][1] * Ql[h * 64 + c0 + 1] +
                 o[j][2] * Ql[h * 64 + c0 + 2] + o[j][3] * Ql[h * 64 + c0 + 3];
      float pk = o[j][0] * Kl[h * 64 + c0] + o[j][1] * Kl[h * 64 + c0 + 1] +
                 o[j][2] * Kl[h * 64 + c0 + 2] + o[j][3] * Kl[h * 64 + c0 + 3];
#pragma unroll
      for (int off = 1; off < 16; off <<= 1) {
        pq += __shfl_xor(pq, off);
        pk += __shfl_xor(pk, off);
      }
      if ((tid & 15) == 0) {
        qs[(size_t)(nbase + j) * 4 + h] = pq;
        ks[(size_t)(nbase + j) * 4 + h] = pk;
      }
    }
  }
}

__global__ void k_groups(const int* full, const void* mask, const int* tgt, const int* mult,
                         const float* qs, const float* ks, const void* att_b, void* outv,
                         const int* flg) {
  int f = flg[0], mbyte = flg[1];
  int g = blockIdx.x;
  int lane = threadIdx.x;
  int k = lane >> 2, h = lane & 3;
  int t = tgt[g];
  int idx = full[g * KK + k];
  int mk = MK(mask, g * KK + k, mbyte);
  float bh = LD(att_b, h, f);
  float qt = qs[t * 4 + h];
  float sc = sigm(qt + ks[idx * 4 + h] + bh);
  int is_tgt = (idx == t) && mk;
  int nbr = mk && !is_tgt;
  unsigned long long bal = __ballot(nbr != 0);
  int degm1 = (int)(__popcll(bal) >> 2);
  float ssum = nbr ? sc : 0.f;
  for (int off = 4; off < 64; off <<= 1) ssum += __shfl_xor(ssum, off);
  ssum /= (float)(degm1 > 1 ? degm1 : 1);
  float trg = sigm(qt + ks[t * 4 + h] + bh);
  float mxv = fmaxf(ssum, trg);
  float e0 = expf(ssum - mxv), e1 = expf(trg - mxv);
  float tw0 = e0 / (e0 + e1), tw1 = e1 / (e0 + e1);
  float msc = nbr ? sc : -1e30f;
  float m = msc;
  for (int off = 4; off < 64; off <<= 1) m = fmaxf(m, __shfl_xor(m, off));
  float ex = expf(msc - m);
  float den = ex;
  for (int off = 4; off < 64; off <<= 1) den += __shfl_xor(den, off);
  float w = ex / den * tw0 * (float)mult[g];
  float res = is_tgt ? tw1 : (nbr ? w : 0.f);
  if (degm1 == 0) res = 0.f;
  ST(outv, g * 64 + k * 4 + h, f, res);
}

extern "C" void kernel_launch(void* const* d_in, const int* in_sizes, int n_in,
                              void* d_out, int out_size, void* d_ws, size_t ws_size,
                              hipStream_t stream) {
  const int* edge = (const int*)d_in[0];
  const int* esrc = edge;
  const int* edst = edge + EE;
  const int* vn_colors = (const int*)d_in[1];
  const int* group_full = (const int*)d_in[2];
  const void* group_mask = d_in[3];
  const int* group_tgt = (const int*)d_in[4];
  const int* group_mult = (const int*)d_in[5];
  const void* vn_prefix = d_in[6];
  const void* fn_embed = d_in[7];
  const void* v2f_msgs = d_in[8];
  const void* v2f_hidden = d_in[9];
  const void* f2v_msgs = d_in[10];
  const void* f2v_hidden = d_in[11];
  const void* msg_prefix = d_in[12];
  const void* emb = d_in[13];
  const void* gv_wih = d_in[14];
  const void* gv_whh = d_in[15];
  const void* gv_bih = d_in[16];
  const void* gv_bhh = d_in[17];
  const void* gf_wih = d_in[18];
  const void* gf_whh = d_in[19];
  const void* gf_bih = d_in[20];
  const void* gf_bhh = d_in[21];
  const void* W1 = d_in[22];
  const void* a1s = d_in[23];
  const void* a1d = d_in[24];
  const void* b1 = d_in[25];
  const void* W2 = d_in[26];
  const void* a2s = d_in[27];
  const void* a2d = d_in[28];
  const void* b2 = d_in[29];
  const void* W3 = d_in[30];
  const void* a3s = d_in[31];
  const void* a3d = d_in[32];
  const void* b3 = d_in[33];
  const void* W4 = d_in[34];
  const void* a4s = d_in[35];
  const void* a4d = d_in[36];
  const void* b4 = d_in[37];
  const void* att_wq = d_in[38];
  const void* att_wk = d_in[39];
  const void* att_ws = d_in[40];
  const void* att_b = d_in[41];

  char* w = (char*)d_ws;
  size_t off = 0;
  auto carve = [&](size_t bytes) -> void* {
    void* p = w + off;
    off += (bytes + 255) & ~(size_t)255;
    return p;
  };
  int* flags = (int*)carve(16);
  float* Wt = (float*)carve((size_t)2 * 77 * 192 * 4);
  float* hidcat = (float*)carve((size_t)2 * NM * EMB * 4);
  float* xB = (float*)carve((size_t)NN * 64 * 4);
  float* scr = (float*)carve((size_t)NN * 128 * 4);
  float* a_sA = (float*)carve((size_t)NN * 4 * 4);
  float* a_dA = (float*)carve((size_t)NN * 4 * 4);
  float* a_sB = (float*)carve((size_t)NN * 4 * 4);
  float* a_dB = (float*)carve((size_t)NN * 4 * 4);
  int* deg = (int*)carve((size_t)2 * NN * 4);  // deg + cnt adjacent, zeroed in k_precomp
  int* cnt = deg + NN;
  int* rowptr = (int*)carve((size_t)(NN + 1) * 4);
  int* bsum = (int*)carve(128 * 4);
  int* col = (int*)carve((size_t)EE * 4);
  float* qs = (float*)carve((size_t)NF * 4 * 4);
  float* ks = (float*)carve((size_t)NF * 4 * 4);
  float* wqv = (float*)carve(256 * 4);
  float* wkv = (float*)carve(256 * 4);
  float* waS = (float*)carve(128 * 4);
  float* waD = (float*)carve(128 * 4);

  k_detect<<<1, 64, 0, stream>>>(fn_embed, group_mask, flags);
  k_precomp<<<118 + (2 * NN + 255) / 256, 256, 0, stream>>>(
      gv_wih, gv_whh, gf_wih, gf_whh, W4, a4s, a4d,
      att_wq, att_wk, att_ws, Wt, waS, waD, wqv, wkv, deg, flags);
  k_gru2<<<768, 256, 0, stream>>>(v2f_msgs, v2f_hidden, f2v_msgs, f2v_hidden,
                                  gv_bih, gv_bhh, gf_bih, gf_bhh, Wt, hidcat, d_out, flags);
  k_deg<<<EE / 256, 256, 0, stream>>>(edst, deg);
  k_scan1<<<72, 512, 0, stream>>>(deg, rowptr, bsum);
  k_scan23<<<1, 512, 0, stream>>>(rowptr, bsum, 72);
  k_fill<<<EE / 256, 256, 0, stream>>>(esrc, edst, rowptr, cnt, col);

  // L1: assemble + x@W1 + coef1 -> xl1 in scr, coefs in A
  k_xl1<<<NN / 8, 256, 0, stream>>>(vn_prefix, vn_colors, emb, fn_embed, msg_prefix,
                                    hidcat, W1, a1s, a1d, scr, a_sA, a_dA, flags);
  // gather L1 (+xl2+coef2): scr,A -> xB,B
  k_gather13<0><<<NN / 16, 256, 0, stream>>>(rowptr, col, a_sA, a_dA, scr, b1,
                                             W2, a2s, a2d, nullptr, nullptr,
                                             xB, nullptr, a_sB, a_dB, flags);
  // gather L2 (+xl3+coef3): xB,B -> scr,A
  k_gather13<0><<<NN / 16, 256, 0, stream>>>(rowptr, col, a_sB, a_dB, xB, b2,
                                             W3, a3s, a3d, nullptr, nullptr,
                                             scr, nullptr, a_sA, a_dA, flags);
  // gather L3 (+act out + coef4): scr,A -> xB (act), B (coef4)
  k_gather13<1><<<NN / 16, 256, 0, stream>>>(rowptr, col, a_sA, a_dA, scr, b3,
                                             nullptr, nullptr, nullptr, waS, waD,
                                             nullptr, xB, a_sB, a_dB, flags);
  // L4 (only fn rows): gather4 -> agg in scr; l4_out + fused qk -> qs/ks
  k_gather4<<<NF / 16, 256, 0, stream>>>(rowptr, col, a_sB, a_dB, xB, scr);
  k_l4_out<<<NF / 64, 256, 0, stream>>>(scr, W4, b4, wqv, wkv, qs, ks, flags);

  k_groups<<<GG, 64, 0, stream>>>(group_full, group_mask, group_tgt, group_mult,
                                  qs, ks, att_b, d_out, flags);
}

// Round 13
// 192.681 us; speedup vs baseline: 1.1864x; 1.0269x over previous
//
#include <hip/hip_runtime.h>
#include <hip/hip_bf16.h>

#define NV 8192
#define NF 4096
#define NM 12288
#define PFX 3
#define DOM 16
#define EMB 61
#define NN 36864
#define EE 262144
#define GG 8192
#define KK 16
#define OUT0 524288
#define ECAP 32

typedef __hip_bfloat16 bf16;
__device__ __forceinline__ float b2f(bf16 x) { return __bfloat162float(x); }
__device__ __forceinline__ float lrelu(float x, float s) { return x > 0.f ? x : s * x; }
__device__ __forceinline__ float sigm(float x) { return 1.f / (1.f + expf(-x)); }
__device__ __forceinline__ float fexp(float x) { return __expf(fminf(x, 60.f)); }
__device__ __forceinline__ float LD(const void* p, int i, int f) {
  return f ? ((const float*)p)[i] : b2f(((const bf16*)p)[i]);
}
__device__ __forceinline__ void ST(void* p, int i, int f, float v) {
  if (f) ((float*)p)[i] = v; else ((bf16*)p)[i] = __float2bfloat16(v);
}
__device__ __forceinline__ int MK(const void* p, int i, int bytey) {
  return bytey ? (int)((const signed char*)p)[i] : ((const int*)p)[i];
}
__device__ int detect_f(const void* fn) {
  int wild = 0;
  const bf16* h = (const bf16*)fn;
  for (int i = 0; i < 128; ++i) {
    float x = b2f(h[i]);
    float a = fabsf(x);
    if (a != a || a > 1e4f || (x != 0.f && a < 1e-8f)) ++wild;
  }
  return (wild >= 8) ? 1 : 0;
}

// -------- fused precompute: Wt (0-115), waS/waD (116), wqk+flags (117), zero deg/cnt (118+)
__global__ void k_precomp(const void* gv_wih, const void* gv_whh,
                          const void* gf_wih, const void* gf_whh,
                          const void* W4, const void* a4s, const void* a4d,
                          const void* wq, const void* wk, const void* ws,
                          const void* fn_embed, const void* mask,
                          float* Wt, float* waS, float* waD, float* wqv, float* wkv,
                          int* deg0, int* flags) {
  int blk = blockIdx.x, tid = threadIdx.x;
  if (blk >= 118) {
    int t = (blk - 118) * 256 + tid;
    if (t < 2 * NN) deg0[t] = 0;
    return;
  }
  __shared__ int sf;
  if (tid == 0) sf = detect_f(fn_embed);
  __syncthreads();
  int f = sf;
  if (blk < 116) {
    int t = blk * 256 + tid;
    if (t < 2 * 77 * 192) {
      int dir = t / (77 * 192);
      int rem = t - dir * 77 * 192;
      int d = rem / 192, o = rem - d * 192;
      const void* wih = dir ? gf_wih : gv_wih;
      const void* whh = dir ? gf_whh : gv_whh;
      float v = 0.f;
      if (o < 183) v = (d < 16) ? LD(wih, o * 16 + d, f) : LD(whh, o * 61 + (d - 16), f);
      Wt[t] = v;
    }
  } else if (blk == 116) {
    int isD = tid >= 128;
    int u = tid & 127;
    int h = u >> 5, k = u & 31;
    const void* av = isD ? a4d : a4s;
    float acc = 0.f;
    for (int c = 0; c < 64; ++c) acc += LD(W4, k * 256 + h * 64 + c, f) * LD(av, h * 64 + c, f);
    (isD ? waD : waS)[h * 32 + k] = acc;
  } else {
    if (tid == 0) {
      flags[0] = f;
      const int* mi = (const int*)mask;
      int bytey = 0;
      for (int i = 0; i < 64; ++i)
        if ((unsigned)mi[i] > 1u) bytey = 1;
      flags[1] = bytey;
    }
    int h = tid >> 6, d = tid & 63;
    float q = 0.f, k = 0.f;
    for (int e = 0; e < 64; ++e) {
      q += LD(wq, h * 4096 + d * 64 + e, f) * LD(ws, h * 128 + e, f);
      k += LD(wk, h * 4096 + d * 64 + e, f) * LD(ws, h * 128 + 64 + e, f);
    }
    wqv[h * 64 + d] = q;
    wkv[h * 64 + d] = k;
  }
}

// ---------------- GRU v6: 32 rows/block, coalesced W loads ----------------
__global__ __launch_bounds__(256) void k_gru2(
    const void* v2f_msgs, const void* v2f_hid, const void* f2v_msgs, const void* f2v_hid,
    const void* gv_bih, const void* gv_bhh, const void* gf_bih, const void* gf_bhh,
    const float* Wt, float* hidcat, void* outv, const int* flg) {
  int f = flg[0];
  int blk = blockIdx.x;
  int dir = blk >= 384;
  int loc = dir ? blk - 384 : blk;
  int gr0 = loc * 32;
  const void* msgs = dir ? f2v_msgs : v2f_msgs;
  const void* hid = dir ? f2v_hid : v2f_hid;
  const void* bih = dir ? gf_bih : gv_bih;
  const void* bhh = dir ? gf_bhh : gv_bhh;
  const float* W = Wt + dir * 77 * 192;

  __shared__ float GA[32 * 192];
  __shared__ float GB[32 * 192];
  float* F = GA;

  int tid = threadIdx.x;
  for (int idx = tid; idx < 32 * 16; idx += 256) {
    int r = idx >> 4, d = idx & 15;
    F[d * 36 + r] = LD(msgs, (gr0 + r) * DOM + d, f);
  }
  for (int idx = tid; idx < 32 * 61; idx += 256) {
    int r = idx / 61, d = idx - r * 61;
    F[(16 + d) * 36 + r] = LD(hid, gr0 * 61 + idx, f);
  }
  __syncthreads();

  int lane = tid & 63, w = tid >> 6;
  int r0 = w * 8;
  int act = lane < 48;
  int o0 = act ? lane * 4 : 0;
  float accA[32], accB[32];
#pragma unroll
  for (int i = 0; i < 32; ++i) { accA[i] = 0.f; accB[i] = 0.f; }

#pragma unroll 4
  for (int d = 0; d < 16; ++d) {
    float4 wv = *(const float4*)&W[d * 192 + o0];
    float4 fa = *(const float4*)&F[d * 36 + r0];
    float4 fb = *(const float4*)&F[d * 36 + r0 + 4];
    float fr[8] = {fa.x, fa.y, fa.z, fa.w, fb.x, fb.y, fb.z, fb.w};
#pragma unroll
    for (int ri = 0; ri < 8; ++ri) {
      accA[ri * 4 + 0] += wv.x * fr[ri];
      accA[ri * 4 + 1] += wv.y * fr[ri];
      accA[ri * 4 + 2] += wv.z * fr[ri];
      accA[ri * 4 + 3] += wv.w * fr[ri];
    }
  }
#pragma unroll 4
  for (int d = 16; d < 77; ++d) {
    float4 wv = *(const float4*)&W[d * 192 + o0];
    float4 fa = *(const float4*)&F[d * 36 + r0];
    float4 fb = *(const float4*)&F[d * 36 + r0 + 4];
    float fr[8] = {fa.x, fa.y, fa.z, fa.w, fb.x, fb.y, fb.z, fb.w};
#pragma unroll
    for (int ri = 0; ri < 8; ++ri) {
      accB[ri * 4 + 0] += wv.x * fr[ri];
      accB[ri * 4 + 1] += wv.y * fr[ri];
      accB[ri * 4 + 2] += wv.z * fr[ri];
      accB[ri * 4 + 3] += wv.w * fr[ri];
    }
  }
  __syncthreads();

  if (act) {
    float bi[4], bh[4];
#pragma unroll
    for (int c = 0; c < 4; ++c) {
      int o = o0 + c;
      bi[c] = (o < 183) ? LD(bih, o, f) : 0.f;
      bh[c] = (o < 183) ? LD(bhh, o, f) : 0.f;
    }
#pragma unroll
    for (int ri = 0; ri < 8; ++ri) {
      int r = r0 + ri;
      float4 ga, gb;
      ga.x = accA[ri * 4 + 0] + bi[0]; ga.y = accA[ri * 4 + 1] + bi[1];
      ga.z = accA[ri * 4 + 2] + bi[2]; ga.w = accA[ri * 4 + 3] + bi[3];
      gb.x = accB[ri * 4 + 0] + bh[0]; gb.y = accB[ri * 4 + 1] + bh[1];
      gb.z = accB[ri * 4 + 2] + bh[2]; gb.w = accB[ri * 4 + 3] + bh[3];
      *(float4*)&GA[r * 192 + o0] = ga;
      *(float4*)&GB[r * 192 + o0] = gb;
    }
  }
  __syncthreads();

  int j = tid & 63, rq = tid >> 6;
  if (j < 61) {
    for (int rr = 0; rr < 8; ++rr) {
      int r = rq * 8 + rr;
      float gr = sigm(GA[r * 192 + j] + GB[r * 192 + j]);
      float gz = sigm(GA[r * 192 + 61 + j] + GB[r * 192 + 61 + j]);
      float gn = tanhf(GA[r * 192 + 122 + j] + gr * GB[r * 192 + 122 + j]);
      float hold = LD(hid, (gr0 + r) * 61 + j, f);
      float hn = (1.f - gz) * gn + gz * hold;
      int b = dir * NM + gr0 + r;
      hidcat[b * 61 + j] = hn;
      ST(outv, OUT0 + b * 61 + j, f, hn);
    }
  }
}

// ---------------- CSR build ----------------
__global__ void k_deg(const int* dst, int* deg) {
  int e = blockIdx.x * blockDim.x + threadIdx.x;
  if (e < EE) atomicAdd(&deg[dst[e]], 1);
}
__global__ void k_scan1(const int* deg, int* rowptr, int* bsum) {
  __shared__ int s[512];
  int g = blockIdx.x * 512 + threadIdx.x;
  int v = (g < NN) ? deg[g] : 0;
  s[threadIdx.x] = v;
  __syncthreads();
  for (int off = 1; off < 512; off <<= 1) {
    int t = (threadIdx.x >= off) ? s[threadIdx.x - off] : 0;
    __syncthreads();
    s[threadIdx.x] += t;
    __syncthreads();
  }
  if (g < NN) rowptr[g] = s[threadIdx.x] - v;
  if (threadIdx.x == 511) bsum[blockIdx.x] = s[511];
}
__global__ void k_scan23(int* rowptr, const int* bsum, int nb) {
  __shared__ int ps[128];
  int tid = threadIdx.x;
  int v = 0;
  if (tid < 128) { v = (tid < nb) ? bsum[tid] : 0; ps[tid] = v; }
  __syncthreads();
  for (int off = 1; off < 128; off <<= 1) {
    int t = 0;
    if (tid < 128 && tid >= off) t = ps[tid - off];
    __syncthreads();
    if (tid < 128) ps[tid] += t;
    __syncthreads();
  }
  if (tid < 128) ps[tid] -= v;
  __syncthreads();
  for (int g = tid; g < NN; g += 512) rowptr[g] += ps[g >> 9];
  if (tid == 0) rowptr[NN] = EE;
}
__global__ void k_fill(const int* src, const int* dst, const int* rowptr, int* cnt, int* col) {
  int e = blockIdx.x * blockDim.x + threadIdx.x;
  if (e < EE) {
    int d = dst[e];
    int pos = rowptr[d] + atomicAdd(&cnt[d], 1);
    col[pos] = src[e];
  }
}

// ---------------- L1: fused assemble + x@W1 + coef ----------------
__global__ __launch_bounds__(256) void k_xl1(
    const void* vn_prefix, const int* vn_colors, const void* emb, const void* fn_embed,
    const void* msg_prefix, const float* hidcat, const void* W1, const void* a1s,
    const void* a1d, float* xl, float* a_s, float* a_d, const int* flg) {
  int f = flg[0];
  __shared__ float Wl[64 * 32];
  __shared__ float X[8][64];
  int tid = threadIdx.x;
  for (int t = tid; t < 2048; t += 256) Wl[t] = LD(W1, t, f);
  for (int t = tid; t < 512; t += 256) {
    int r = t >> 6, c = t & 63;
    int i = blockIdx.x * 8 + r;
    float v;
    if (i < NV) {
      v = (c < PFX) ? LD(vn_prefix, i * PFX + c, f) : LD(emb, vn_colors[i] * EMB + (c - PFX), f);
    } else if (i < NV + NF) {
      v = LD(fn_embed, (size_t)(i - NV) * 64 + c, f);
    } else {
      int jj = i - NV - NF;
      v = (c < PFX) ? LD(msg_prefix, jj * PFX + c, f) : hidcat[jj * EMB + (c - PFX)];
    }
    X[r][c] = v;
  }
  __syncthreads();
  int j = tid & 31, r = tid >> 5;
  int i = blockIdx.x * 8 + r;
  float acc = 0.f;
#pragma unroll
  for (int k = 0; k < 64; ++k) acc += X[r][k] * Wl[k * 32 + j];
  xl[(size_t)i * 32 + j] = acc;
  float sw = LD(a1s, j, f), dw = LD(a1d, j, f);
  float p = acc * sw, q = acc * dw;
#pragma unroll
  for (int off = 1; off < 8; off <<= 1) {
    p += __shfl_xor(p, off);
    q += __shfl_xor(q, off);
  }
  if ((j & 7) == 0) {
    a_s[(size_t)i * 4 + (j >> 3)] = p;
    a_d[(size_t)i * 4 + (j >> 3)] = q;
  }
}

// ---------------- GAT gather (max-free softmax, ECAP=32): MODE0/MODE1 ----------------
template <int MODE>
__global__ __launch_bounds__(256) void k_gather13(
    const int* rowptr, const int* col, const float* a_s, const float* a_d,
    const float* xl, const void* bias,
    const void* Wn, const void* asn_, const void* adn_,      // MODE0
    const float* waS, const float* waD,                       // MODE1
    float* xl_next, float* xout, float* as_out, float* ad_out, const int* flg) {
  int f = flg[0];
  __shared__ int colb[16][ECAP];
  __shared__ float4 eb[16][ECAP];
  __shared__ float Wn_l[32 * 32];
  __shared__ float an_s[32], an_d[32];
  __shared__ float Xr[16][33];
  __shared__ float SwaS[128], SwaD[128];
  int tid = threadIdx.x;
  if (MODE == 0) {
    for (int t = tid; t < 1024; t += 256) Wn_l[t] = LD(Wn, t, f);
    if (tid < 32) { an_s[tid] = LD(asn_, tid, f); an_d[tid] = LD(adn_, tid, f); }
  } else {
    if (tid < 128) { SwaS[tid] = waS[tid]; SwaD[tid] = waD[tid]; }
  }
  int g = tid >> 4, l = tid & 15;
  int i = blockIdx.x * 16 + g;
  int beg = rowptr[i], end = rowptr[i + 1];
  int deg = end - beg;
  float4 adv = *(const float4*)(a_d + (size_t)i * 4);
  float4 asv = *(const float4*)(a_s + (size_t)i * 4);
  float ad[4] = {adv.x, adv.y, adv.z, adv.w};
  float exS[4];
  {
    float asl[4] = {asv.x, asv.y, asv.z, asv.w};
#pragma unroll
    for (int h = 0; h < 4; ++h) exS[h] = fexp(lrelu(asl[h] + ad[h], 0.2f));
  }
  float den[4] = {0.f, 0.f, 0.f, 0.f};
  int c0 = l, c1 = l + 16;
  int h0 = l >> 3, h1 = 2 + (l >> 3);
  float acc0, acc1;

  if (deg <= ECAP) {
    for (int s = l; s < deg; s += 16) {
      int j = col[beg + s];
      colb[g][s] = j;
      float4 aj = *(const float4*)(a_s + (size_t)j * 4);
      float x0 = fexp(lrelu(aj.x + ad[0], 0.2f));
      float x1 = fexp(lrelu(aj.y + ad[1], 0.2f));
      float x2 = fexp(lrelu(aj.z + ad[2], 0.2f));
      float x3 = fexp(lrelu(aj.w + ad[3], 0.2f));
      eb[g][s] = make_float4(x0, x1, x2, x3);
      den[0] += x0; den[1] += x1; den[2] += x2; den[3] += x3;
    }
#pragma unroll
    for (int off = 1; off < 16; off <<= 1)
#pragma unroll
      for (int h = 0; h < 4; ++h) den[h] += __shfl_xor(den[h], off);
#pragma unroll
    for (int h = 0; h < 4; ++h) den[h] += exS[h];
    acc0 = exS[h0] * xl[(size_t)i * 32 + c0];
    acc1 = exS[h1] * xl[(size_t)i * 32 + c1];
#pragma unroll 2
    for (int s = 0; s < deg; ++s) {
      int j = colb[g][s];
      float4 e4 = eb[g][s];
      float w0 = h0 ? e4.y : e4.x;
      float w1 = (l >> 3) ? e4.w : e4.z;
      acc0 += w0 * xl[(size_t)j * 32 + c0];
      acc1 += w1 * xl[(size_t)j * 32 + c1];
    }
  } else {
    for (int s = l; s < deg; s += 16) {
      int j = col[beg + s];
      float4 aj = *(const float4*)(a_s + (size_t)j * 4);
      den[0] += fexp(lrelu(aj.x + ad[0], 0.2f));
      den[1] += fexp(lrelu(aj.y + ad[1], 0.2f));
      den[2] += fexp(lrelu(aj.z + ad[2], 0.2f));
      den[3] += fexp(lrelu(aj.w + ad[3], 0.2f));
    }
#pragma unroll
    for (int off = 1; off < 16; off <<= 1)
#pragma unroll
      for (int h = 0; h < 4; ++h) den[h] += __shfl_xor(den[h], off);
#pragma unroll
    for (int h = 0; h < 4; ++h) den[h] += exS[h];
    acc0 = exS[h0] * xl[(size_t)i * 32 + c0];
    acc1 = exS[h1] * xl[(size_t)i * 32 + c1];
    for (int s = 0; s < deg; ++s) {
      int j = col[beg + s];
      float e0 = fexp(lrelu(a_s[(size_t)j * 4 + h0] + ad[h0], 0.2f));
      float e1 = fexp(lrelu(a_s[(size_t)j * 4 + h1] + ad[h1], 0.2f));
      acc0 += e0 * xl[(size_t)j * 32 + c0];
      acc1 += e1 * xl[(size_t)j * 32 + c1];
    }
  }
  float v0 = lrelu(acc0 / den[h0] + LD(bias, c0, f), 0.01f);
  float v1 = lrelu(acc1 / den[h1] + LD(bias, c1, f), 0.01f);

  if (MODE == 0) {
    Xr[g][c0] = v0;
    Xr[g][c1] = v1;
    __syncthreads();
    float n0 = 0.f, n1 = 0.f;
#pragma unroll
    for (int k = 0; k < 32; ++k) {
      float xv = Xr[g][k];
      n0 += xv * Wn_l[k * 32 + c0];
      n1 += xv * Wn_l[k * 32 + c1];
    }
    xl_next[(size_t)i * 32 + c0] = n0;
    xl_next[(size_t)i * 32 + c1] = n1;
    float p0 = n0 * an_s[c0], q0 = n0 * an_d[c0];
    float p1 = n1 * an_s[c1], q1 = n1 * an_d[c1];
#pragma unroll
    for (int off = 1; off < 8; off <<= 1) {
      p0 += __shfl_xor(p0, off); q0 += __shfl_xor(q0, off);
      p1 += __shfl_xor(p1, off); q1 += __shfl_xor(q1, off);
    }
    if ((l & 7) == 0) {
      as_out[(size_t)i * 4 + h0] = p0;
      ad_out[(size_t)i * 4 + h0] = q0;
      as_out[(size_t)i * 4 + h1] = p1;
      ad_out[(size_t)i * 4 + h1] = q1;
    }
  } else {
    xout[(size_t)i * 32 + c0] = v0;
    xout[(size_t)i * 32 + c1] = v1;
    float pS[4], pD[4];
#pragma unroll
    for (int h = 0; h < 4; ++h) {
      pS[h] = v0 * SwaS[h * 32 + c0] + v1 * SwaS[h * 32 + c1];
      pD[h] = v0 * SwaD[h * 32 + c0] + v1 * SwaD[h * 32 + c1];
    }
#pragma unroll
    for (int off = 1; off < 16; off <<= 1)
#pragma unroll
      for (int h = 0; h < 4; ++h) { pS[h] += __shfl_xor(pS[h], off); pD[h] += __shfl_xor(pD[h], off); }
    if (l == 0) {
#pragma unroll
      for (int h = 0; h < 4; ++h) {
        as_out[(size_t)i * 4 + h] = pS[h];
        ad_out[(size_t)i * 4 + h] = pD[h];
      }
    }
  }
}

// ---------------- gather4 (max-free, ECAP=32): only rows [NV, NV+NF) ----------------
__global__ __launch_bounds__(256) void k_gather4(const int* rowptr, const int* col,
                                                 const float* a_s, const float* a_d,
                                                 const float* x, float* agg) {
  __shared__ int colb[16][ECAP];
  __shared__ float4 eb[16][ECAP];
  int tid = threadIdx.x;
  int g = tid >> 4, l = tid & 15;
  int i = NV + blockIdx.x * 16 + g;
  int beg = rowptr[i], end = rowptr[i + 1];
  int deg = end - beg;
  float4 adv = *(const float4*)(a_d + (size_t)i * 4);
  float4 asv = *(const float4*)(a_s + (size_t)i * 4);
  float ad[4] = {adv.x, adv.y, adv.z, adv.w};
  float exS[4];
  {
    float asl[4] = {asv.x, asv.y, asv.z, asv.w};
#pragma unroll
    for (int h = 0; h < 4; ++h) exS[h] = fexp(lrelu(asl[h] + ad[h], 0.2f));
  }
  float den[4] = {0.f, 0.f, 0.f, 0.f};
  int k0 = l, k1 = l + 16;
  float acc[4][2];

  if (deg <= ECAP) {
    for (int s = l; s < deg; s += 16) {
      int j = col[beg + s];
      colb[g][s] = j;
      float4 aj = *(const float4*)(a_s + (size_t)j * 4);
      float x0 = fexp(lrelu(aj.x + ad[0], 0.2f));
      float x1 = fexp(lrelu(aj.y + ad[1], 0.2f));
      float x2 = fexp(lrelu(aj.z + ad[2], 0.2f));
      float x3 = fexp(lrelu(aj.w + ad[3], 0.2f));
      eb[g][s] = make_float4(x0, x1, x2, x3);
      den[0] += x0; den[1] += x1; den[2] += x2; den[3] += x3;
    }
#pragma unroll
    for (int off = 1; off < 16; off <<= 1)
#pragma unroll
      for (int h = 0; h < 4; ++h) den[h] += __shfl_xor(den[h], off);
    float xs0 = x[(size_t)i * 32 + k0], xs1 = x[(size_t)i * 32 + k1];
#pragma unroll
    for (int h = 0; h < 4; ++h) {
      den[h] += exS[h];
      acc[h][0] = exS[h] * xs0;
      acc[h][1] = exS[h] * xs1;
    }
#pragma unroll 2
    for (int s = 0; s < deg; ++s) {
      int j = colb[g][s];
      float4 e4 = eb[g][s];
      float xv0 = x[(size_t)j * 32 + k0], xv1 = x[(size_t)j * 32 + k1];
      acc[0][0] += e4.x * xv0; acc[0][1] += e4.x * xv1;
      acc[1][0] += e4.y * xv0; acc[1][1] += e4.y * xv1;
      acc[2][0] += e4.z * xv0; acc[2][1] += e4.z * xv1;
      acc[3][0] += e4.w * xv0; acc[3][1] += e4.w * xv1;
    }
  } else {
    for (int s = l; s < deg; s += 16) {
      int j = col[beg + s];
      float4 aj = *(const float4*)(a_s + (size_t)j * 4);
      den[0] += fexp(lrelu(aj.x + ad[0], 0.2f));
      den[1] += fexp(lrelu(aj.y + ad[1], 0.2f));
      den[2] += fexp(lrelu(aj.z + ad[2], 0.2f));
      den[3] += fexp(lrelu(aj.w + ad[3], 0.2f));
    }
#pragma unroll
    for (int off = 1; off < 16; off <<= 1)
#pragma unroll
      for (int h = 0; h < 4; ++h) den[h] += __shfl_xor(den[h], off);
    float xs0 = x[(size_t)i * 32 + k0], xs1 = x[(size_t)i * 32 + k1];
#pragma unroll
    for (int h = 0; h < 4; ++h) {
      den[h] += exS[h];
      acc[h][0] = exS[h] * xs0;
      acc[h][1] = exS[h] * xs1;
    }
    for (int s = 0; s < deg; ++s) {
      int j = col[beg + s];
      float4 aj = *(const float4*)(a_s + (size_t)j * 4);
      float e0 = fexp(lrelu(aj.x + ad[0], 0.2f));
      float e1 = fexp(lrelu(aj.y + ad[1], 0.2f));
      float e2 = fexp(lrelu(aj.z + ad[2], 0.2f));
      float e3 = fexp(lrelu(aj.w + ad[3], 0.2f));
      float xv0 = x[(size_t)j * 32 + k0], xv1 = x[(size_t)j * 32 + k1];
      acc[0][0] += e0 * xv0; acc[0][1] += e0 * xv1;
      acc[1][0] += e1 * xv0; acc[1][1] += e1 * xv1;
      acc[2][0] += e2 * xv0; acc[2][1] += e2 * xv1;
      acc[3][0] += e3 * xv0; acc[3][1] += e3 * xv1;
    }
  }
#pragma unroll
  for (int h = 0; h < 4; ++h) {
    agg[(size_t)i * 128 + h * 32 + k0] = acc[h][0] / den[h];
    agg[(size_t)i * 128 + h * 32 + k1] = acc[h][1] / den[h];
  }
}

// ---------------- L4 epilogue + fused qk: only rows [NV, NV+NF) ----------------
__global__ __launch_bounds__(256) void k_l4_out(const float* agg, const void* W4, const void* b4,
                                                const float* wqv, const float* wkv,
                                                float* qs, float* ks, const int* flg) {
  int f = flg[0];
  __shared__ float Wl[128 * 64];
  __shared__ float Al[64][132];
  __shared__ float Ql[256], Kl[256];
  int tid = threadIdx.x;
  int R0 = NV + blockIdx.x * 64;
  for (int t = tid; t < 128 * 64; t += 256) {
    int K = t >> 6, c = t & 63;
    int h = K >> 5, k = K & 31;
    Wl[t] = LD(W4, k * 256 + h * 64 + c, f);
  }
  {
    const float4* ag4 = (const float4*)(agg + (size_t)R0 * 128);
    for (int t = tid; t < 2048; t += 256) {
      int r = t >> 5, k4 = (t & 31) << 2;
      float4 v = ag4[t];
      *(float4*)&Al[r][k4] = v;
    }
  }
  if (tid < 256) { Ql[tid] = wqv[tid]; Kl[tid] = wkv[tid]; }
  __syncthreads();
  int c0 = (tid & 15) << 2, r0 = (tid >> 4) << 2;
  float acc[4][4];
#pragma unroll
  for (int j = 0; j < 4; ++j)
#pragma unroll
    for (int i = 0; i < 4; ++i) acc[j][i] = 0.f;
#pragma unroll 4
  for (int K = 0; K < 128; ++K) {
    float4 wv = *(const float4*)&Wl[K * 64 + c0];
    float a0 = Al[r0][K], a1 = Al[r0 + 1][K], a2 = Al[r0 + 2][K], a3 = Al[r0 + 3][K];
    acc[0][0] += a0 * wv.x; acc[0][1] += a0 * wv.y; acc[0][2] += a0 * wv.z; acc[0][3] += a0 * wv.w;
    acc[1][0] += a1 * wv.x; acc[1][1] += a1 * wv.y; acc[1][2] += a1 * wv.z; acc[1][3] += a1 * wv.w;
    acc[2][0] += a2 * wv.x; acc[2][1] += a2 * wv.y; acc[2][2] += a2 * wv.z; acc[2][3] += a2 * wv.w;
    acc[3][0] += a3 * wv.x; acc[3][1] += a3 * wv.y; acc[3][2] += a3 * wv.z; acc[3][3] += a3 * wv.w;
  }
  float bv[4];
#pragma unroll
  for (int i = 0; i < 4; ++i) bv[i] = LD(b4, c0 + i, f);
  float o[4][4];
#pragma unroll
  for (int j = 0; j < 4; ++j)
#pragma unroll
    for (int i = 0; i < 4; ++i) o[j][i] = lrelu(0.25f * acc[j][i] + bv[i], 0.01f);
  int nbase = R0 - NV + r0;
#pragma unroll
  for (int j = 0; j < 4; ++j) {
#pragma unroll
    for (int h = 0; h < 4; ++h) {
      float pq = o[j][0] * Ql[h * 64 + c0] + o[j][1] * Ql[h * 64 + c0 + 1] +
                 o[j][2] * Ql[h * 64 + c0 + 2] + o[j][3] * Ql[h * 64 + c0 + 3];
      float pk = o[j][0] * Kl[h * 64 + c0] + o[j][1] * Kl[h * 64 + c0 + 1] +
                 o[j][2] * Kl[h * 64 + c0 + 2] + o[j][3] * Kl[h * 64 + c0 + 3];
#pragma unroll
      for (int off = 1; off < 16; off <<= 1) {
        pq += __shfl_xor(pq, off);
        pk += __shfl_xor(pk, off);
      }
      if ((tid & 15) == 0) {
        qs[(size_t)(nbase + j) * 4 + h] = pq;
        ks[(size_t)(nbase + j) * 4 + h] = pk;
      }
    }
  }
}

__global__ void k_groups(const int* full, const void* mask, const int* tgt, const int* mult,
                         const float* qs, const float* ks, const void* att_b, void* outv,
                         const int* flg) {
  int f = flg[0], mbyte = flg[1];
  int g = blockIdx.x;
  int lane = threadIdx.x;
  int k = lane >> 2, h = lane & 3;
  int t = tgt[g];
  int idx = full[g * KK + k];
  int mk = MK(mask, g * KK + k, mbyte);
  float bh = LD(att_b, h, f);
  float qt = qs[t * 4 + h];
  float sc = sigm(qt + ks[idx * 4 + h] + bh);
  int is_tgt = (idx == t) && mk;
  int nbr = mk && !is_tgt;
  unsigned long long bal = __ballot(nbr != 0);
  int degm1 = (int)(__popcll(bal) >> 2);
  float ssum = nbr ? sc : 0.f;
  for (int off = 4; off < 64; off <<= 1) ssum += __shfl_xor(ssum, off);
  ssum /= (float)(degm1 > 1 ? degm1 : 1);
  float trg = sigm(qt + ks[t * 4 + h] + bh);
  float mxv = fmaxf(ssum, trg);
  float e0 = expf(ssum - mxv), e1 = expf(trg - mxv);
  float tw0 = e0 / (e0 + e1), tw1 = e1 / (e0 + e1);
  float msc = nbr ? sc : -1e30f;
  float m = msc;
  for (int off = 4; off < 64; off <<= 1) m = fmaxf(m, __shfl_xor(m, off));
  float ex = expf(msc - m);
  float den = ex;
  for (int off = 4; off < 64; off <<= 1) den += __shfl_xor(den, off);
  float w = ex / den * tw0 * (float)mult[g];
  float res = is_tgt ? tw1 : (nbr ? w : 0.f);
  if (degm1 == 0) res = 0.f;
  ST(outv, g * 64 + k * 4 + h, f, res);
}

extern "C" void kernel_launch(void* const* d_in, const int* in_sizes, int n_in,
                              void* d_out, int out_size, void* d_ws, size_t ws_size,
                              hipStream_t stream) {
  const int* edge = (const int*)d_in[0];
  const int* esrc = edge;
  const int* edst = edge + EE;
  const int* vn_colors = (const int*)d_in[1];
  const int* group_full = (const int*)d_in[2];
  const void* group_mask = d_in[3];
  const int* group_tgt = (const int*)d_in[4];
  const int* group_mult = (const int*)d_in[5];
  const void* vn_prefix = d_in[6];
  const void* fn_embed = d_in[7];
  const void* v2f_msgs = d_in[8];
  const void* v2f_hidden = d_in[9];
  const void* f2v_msgs = d_in[10];
  const void* f2v_hidden = d_in[11];
  const void* msg_prefix = d_in[12];
  const void* emb = d_in[13];
  const void* gv_wih = d_in[14];
  const void* gv_whh = d_in[15];
  const void* gv_bih = d_in[16];
  const void* gv_bhh = d_in[17];
  const void* gf_wih = d_in[18];
  const void* gf_whh = d_in[19];
  const void* gf_bih = d_in[20];
  const void* gf_bhh = d_in[21];
  const void* W1 = d_in[22];
  const void* a1s = d_in[23];
  const void* a1d = d_in[24];
  const void* b1 = d_in[25];
  const void* W2 = d_in[26];
  const void* a2s = d_in[27];
  const void* a2d = d_in[28];
  const void* b2 = d_in[29];
  const void* W3 = d_in[30];
  const void* a3s = d_in[31];
  const void* a3d = d_in[32];
  const void* b3 = d_in[33];
  const void* W4 = d_in[34];
  const void* a4s = d_in[35];
  const void* a4d = d_in[36];
  const void* b4 = d_in[37];
  const void* att_wq = d_in[38];
  const void* att_wk = d_in[39];
  const void* att_ws = d_in[40];
  const void* att_b = d_in[41];

  char* w = (char*)d_ws;
  size_t off = 0;
  auto carve = [&](size_t bytes) -> void* {
    void* p = w + off;
    off += (bytes + 255) & ~(size_t)255;
    return p;
  };
  int* flags = (int*)carve(16);
  float* Wt = (float*)carve((size_t)2 * 77 * 192 * 4);
  float* hidcat = (float*)carve((size_t)2 * NM * EMB * 4);
  float* xB = (float*)carve((size_t)NN * 64 * 4);
  float* scr = (float*)carve((size_t)NN * 128 * 4);
  float* a_sA = (float*)carve((size_t)NN * 4 * 4);
  float* a_dA = (float*)carve((size_t)NN * 4 * 4);
  float* a_sB = (float*)carve((size_t)NN * 4 * 4);
  float* a_dB = (float*)carve((size_t)NN * 4 * 4);
  int* deg = (int*)carve((size_t)2 * NN * 4);  // deg + cnt adjacent, zeroed in k_precomp
  int* cnt = deg + NN;
  int* rowptr = (int*)carve((size_t)(NN + 1) * 4);
  int* bsum = (int*)carve(128 * 4);
  int* col = (int*)carve((size_t)EE * 4);
  float* qs = (float*)carve((size_t)NF * 4 * 4);
  float* ks = (float*)carve((size_t)NF * 4 * 4);
  float* wqv = (float*)carve(256 * 4);
  float* wkv = (float*)carve(256 * 4);
  float* waS = (float*)carve(128 * 4);
  float* waD = (float*)carve(128 * 4);

  k_precomp<<<118 + (2 * NN + 255) / 256, 256, 0, stream>>>(
      gv_wih, gv_whh, gf_wih, gf_whh, W4, a4s, a4d,
      att_wq, att_wk, att_ws, fn_embed, group_mask,
      Wt, waS, waD, wqv, wkv, deg, flags);
  k_gru2<<<768, 256, 0, stream>>>(v2f_msgs, v2f_hidden, f2v_msgs, f2v_hidden,
                                  gv_bih, gv_bhh, gf_bih, gf_bhh, Wt, hidcat, d_out, flags);
  k_deg<<<EE / 256, 256, 0, stream>>>(edst, deg);
  k_scan1<<<72, 512, 0, stream>>>(deg, rowptr, bsum);
  k_scan23<<<1, 512, 0, stream>>>(rowptr, bsum, 72);
  k_fill<<<EE / 256, 256, 0, stream>>>(esrc, edst, rowptr, cnt, col);

  // L1: assemble + x@W1 + coef1 -> xl1 in scr, coefs in A
  k_xl1<<<NN / 8, 256, 0, stream>>>(vn_prefix, vn_colors, emb, fn_embed, msg_prefix,
                                    hidcat, W1, a1s, a1d, scr, a_sA, a_dA, flags);
  // gather L1 (+xl2+coef2): scr,A -> xB,B
  k_gather13<0><<<NN / 16, 256, 0, stream>>>(rowptr, col, a_sA, a_dA, scr, b1,
                                             W2, a2s, a2d, nullptr, nullptr,
                                             xB, nullptr, a_sB, a_dB, flags);
  // gather L2 (+xl3+coef3): xB,B -> scr,A
  k_gather13<0><<<NN / 16, 256, 0, stream>>>(rowptr, col, a_sB, a_dB, xB, b2,
                                             W3, a3s, a3d, nullptr, nullptr,
                                             scr, nullptr, a_sA, a_dA, flags);
  // gather L3 (+act out + coef4): scr,A -> xB (act), B (coef4)
  k_gather13<1><<<NN / 16, 256, 0, stream>>>(rowptr, col, a_sA, a_dA, scr, b3,
                                             nullptr, nullptr, nullptr, waS, waD,
                                             nullptr, xB, a_sB, a_dB, flags);
  // L4 (only fn rows): gather4 -> agg in scr; l4_out + fused qk -> qs/ks
  k_gather4<<<NF / 16, 256, 0, stream>>>(rowptr, col, a_sB, a_dB, xB, scr);
  k_l4_out<<<NF / 64, 256, 0, stream>>>(scr, W4, b4, wqv, wkv, qs, ks, flags);

  k_groups<<<GG, 64, 0, stream>>>(group_full, group_mask, group_tgt, group_mult,
                                  qs, ks, att_b, d_out, flags);
}

// Round 14
// 185.821 us; speedup vs baseline: 1.2302x; 1.0369x over previous
//
#include <hip/hip_runtime.h>
#include <hip/hip_bf16.h>

#define NV 8192
#define NF 4096
#define NM 12288
#define PFX 3
#define DOM 16
#define EMB 61
#define NN 36864
#define EE 262144
#define GG 8192
#define KK 16
#define OUT0 524288
#define ECAP 32

typedef __hip_bfloat16 bf16;
__device__ __forceinline__ float b2f(bf16 x) { return __bfloat162float(x); }
__device__ __forceinline__ float lrelu(float x, float s) { return x > 0.f ? x : s * x; }
__device__ __forceinline__ float sigm(float x) { return 1.f / (1.f + expf(-x)); }
__device__ __forceinline__ float fexp(float x) { return __expf(fminf(x, 60.f)); }
__device__ __forceinline__ float LD(const void* p, int i, int f) {
  return f ? ((const float*)p)[i] : b2f(((const bf16*)p)[i]);
}
__device__ __forceinline__ void ST(void* p, int i, int f, float v) {
  if (f) ((float*)p)[i] = v; else ((bf16*)p)[i] = __float2bfloat16(v);
}
__device__ __forceinline__ int MK(const void* p, int i, int bytey) {
  return bytey ? (int)((const signed char*)p)[i] : ((const int*)p)[i];
}
__device__ int detect_f(const void* fn) {
  int wild = 0;
  const bf16* h = (const bf16*)fn;
  for (int i = 0; i < 128; ++i) {
    float x = b2f(h[i]);
    float a = fabsf(x);
    if (a != a || a > 1e4f || (x != 0.f && a < 1e-8f)) ++wild;
  }
  return (wild >= 8) ? 1 : 0;
}

// -------- fused precompute: Wt (0-115), waS/waD (116), wqk+flags (117), zero deg/cnt (118+)
__global__ void k_precomp(const void* gv_wih, const void* gv_whh,
                          const void* gf_wih, const void* gf_whh,
                          const void* W4, const void* a4s, const void* a4d,
                          const void* wq, const void* wk, const void* ws,
                          const void* fn_embed, const void* mask,
                          float* Wt, float* waS, float* waD, float* wqv, float* wkv,
                          int* deg0, int* flags) {
  int blk = blockIdx.x, tid = threadIdx.x;
  if (blk >= 118) {
    int t = (blk - 118) * 256 + tid;
    if (t < 2 * NN) deg0[t] = 0;
    return;
  }
  __shared__ int sf;
  if (tid == 0) sf = detect_f(fn_embed);
  __syncthreads();
  int f = sf;
  if (blk < 116) {
    int t = blk * 256 + tid;
    if (t < 2 * 77 * 192) {
      int dir = t / (77 * 192);
      int rem = t - dir * 77 * 192;
      int d = rem / 192, o = rem - d * 192;
      const void* wih = dir ? gf_wih : gv_wih;
      const void* whh = dir ? gf_whh : gv_whh;
      float v = 0.f;
      if (o < 183) v = (d < 16) ? LD(wih, o * 16 + d, f) : LD(whh, o * 61 + (d - 16), f);
      Wt[t] = v;
    }
  } else if (blk == 116) {
    int isD = tid >= 128;
    int u = tid & 127;
    int h = u >> 5, k = u & 31;
    const void* av = isD ? a4d : a4s;
    float acc = 0.f;
    for (int c = 0; c < 64; ++c) acc += LD(W4, k * 256 + h * 64 + c, f) * LD(av, h * 64 + c, f);
    (isD ? waD : waS)[h * 32 + k] = acc;
  } else {
    if (tid == 0) {
      flags[0] = f;
      const int* mi = (const int*)mask;
      int bytey = 0;
      for (int i = 0; i < 64; ++i)
        if ((unsigned)mi[i] > 1u) bytey = 1;
      flags[1] = bytey;
    }
    int h = tid >> 6, d = tid & 63;
    float q = 0.f, k = 0.f;
    for (int e = 0; e < 64; ++e) {
      q += LD(wq, h * 4096 + d * 64 + e, f) * LD(ws, h * 128 + e, f);
      k += LD(wk, h * 4096 + d * 64 + e, f) * LD(ws, h * 128 + 64 + e, f);
    }
    wqv[h * 64 + d] = q;
    wkv[h * 64 + d] = k;
  }
}

// ---------------- GRU v6: 32 rows/block, coalesced W loads ----------------
__global__ __launch_bounds__(256) void k_gru2(
    const void* v2f_msgs, const void* v2f_hid, const void* f2v_msgs, const void* f2v_hid,
    const void* gv_bih, const void* gv_bhh, const void* gf_bih, const void* gf_bhh,
    const float* Wt, float* hidcat, void* outv, const int* flg) {
  int f = flg[0];
  int blk = blockIdx.x;
  int dir = blk >= 384;
  int loc = dir ? blk - 384 : blk;
  int gr0 = loc * 32;
  const void* msgs = dir ? f2v_msgs : v2f_msgs;
  const void* hid = dir ? f2v_hid : v2f_hid;
  const void* bih = dir ? gf_bih : gv_bih;
  const void* bhh = dir ? gf_bhh : gv_bhh;
  const float* W = Wt + dir * 77 * 192;

  __shared__ float GA[32 * 192];
  __shared__ float GB[32 * 192];
  float* F = GA;

  int tid = threadIdx.x;
  for (int idx = tid; idx < 32 * 16; idx += 256) {
    int r = idx >> 4, d = idx & 15;
    F[d * 36 + r] = LD(msgs, (gr0 + r) * DOM + d, f);
  }
  for (int idx = tid; idx < 32 * 61; idx += 256) {
    int r = idx / 61, d = idx - r * 61;
    F[(16 + d) * 36 + r] = LD(hid, gr0 * 61 + idx, f);
  }
  __syncthreads();

  int lane = tid & 63, w = tid >> 6;
  int r0 = w * 8;
  int act = lane < 48;
  int o0 = act ? lane * 4 : 0;
  float accA[32], accB[32];
#pragma unroll
  for (int i = 0; i < 32; ++i) { accA[i] = 0.f; accB[i] = 0.f; }

#pragma unroll 4
  for (int d = 0; d < 16; ++d) {
    float4 wv = *(const float4*)&W[d * 192 + o0];
    float4 fa = *(const float4*)&F[d * 36 + r0];
    float4 fb = *(const float4*)&F[d * 36 + r0 + 4];
    float fr[8] = {fa.x, fa.y, fa.z, fa.w, fb.x, fb.y, fb.z, fb.w};
#pragma unroll
    for (int ri = 0; ri < 8; ++ri) {
      accA[ri * 4 + 0] += wv.x * fr[ri];
      accA[ri * 4 + 1] += wv.y * fr[ri];
      accA[ri * 4 + 2] += wv.z * fr[ri];
      accA[ri * 4 + 3] += wv.w * fr[ri];
    }
  }
#pragma unroll 4
  for (int d = 16; d < 77; ++d) {
    float4 wv = *(const float4*)&W[d * 192 + o0];
    float4 fa = *(const float4*)&F[d * 36 + r0];
    float4 fb = *(const float4*)&F[d * 36 + r0 + 4];
    float fr[8] = {fa.x, fa.y, fa.z, fa.w, fb.x, fb.y, fb.z, fb.w};
#pragma unroll
    for (int ri = 0; ri < 8; ++ri) {
      accB[ri * 4 + 0] += wv.x * fr[ri];
      accB[ri * 4 + 1] += wv.y * fr[ri];
      accB[ri * 4 + 2] += wv.z * fr[ri];
      accB[ri * 4 + 3] += wv.w * fr[ri];
    }
  }
  __syncthreads();

  if (act) {
    float bi[4], bh[4];
#pragma unroll
    for (int c = 0; c < 4; ++c) {
      int o = o0 + c;
      bi[c] = (o < 183) ? LD(bih, o, f) : 0.f;
      bh[c] = (o < 183) ? LD(bhh, o, f) : 0.f;
    }
#pragma unroll
    for (int ri = 0; ri < 8; ++ri) {
      int r = r0 + ri;
      float4 ga, gb;
      ga.x = accA[ri * 4 + 0] + bi[0]; ga.y = accA[ri * 4 + 1] + bi[1];
      ga.z = accA[ri * 4 + 2] + bi[2]; ga.w = accA[ri * 4 + 3] + bi[3];
      gb.x = accB[ri * 4 + 0] + bh[0]; gb.y = accB[ri * 4 + 1] + bh[1];
      gb.z = accB[ri * 4 + 2] + bh[2]; gb.w = accB[ri * 4 + 3] + bh[3];
      *(float4*)&GA[r * 192 + o0] = ga;
      *(float4*)&GB[r * 192 + o0] = gb;
    }
  }
  __syncthreads();

  int j = tid & 63, rq = tid >> 6;
  if (j < 61) {
    for (int rr = 0; rr < 8; ++rr) {
      int r = rq * 8 + rr;
      float gr = sigm(GA[r * 192 + j] + GB[r * 192 + j]);
      float gz = sigm(GA[r * 192 + 61 + j] + GB[r * 192 + 61 + j]);
      float gn = tanhf(GA[r * 192 + 122 + j] + gr * GB[r * 192 + 122 + j]);
      float hold = LD(hid, (gr0 + r) * 61 + j, f);
      float hn = (1.f - gz) * gn + gz * hold;
      int b = dir * NM + gr0 + r;
      hidcat[b * 61 + j] = hn;
      ST(outv, OUT0 + b * 61 + j, f, hn);
    }
  }
}

// ---------------- CSR build ----------------
__global__ void k_deg(const int* dst, int* deg) {
  int e = blockIdx.x * blockDim.x + threadIdx.x;
  if (e < EE) atomicAdd(&deg[dst[e]], 1);
}
__global__ void k_scan1(const int* deg, int* rowptr, int* bsum) {
  __shared__ int s[512];
  int g = blockIdx.x * 512 + threadIdx.x;
  int v = (g < NN) ? deg[g] : 0;
  s[threadIdx.x] = v;
  __syncthreads();
  for (int off = 1; off < 512; off <<= 1) {
    int t = (threadIdx.x >= off) ? s[threadIdx.x - off] : 0;
    __syncthreads();
    s[threadIdx.x] += t;
    __syncthreads();
  }
  if (g < NN) rowptr[g] = s[threadIdx.x] - v;
  if (threadIdx.x == 511) bsum[blockIdx.x] = s[511];
}
__global__ void k_scan23(int* rowptr, const int* bsum, int nb) {
  __shared__ int ps[128];
  int tid = threadIdx.x;
  int v = 0;
  if (tid < 128) { v = (tid < nb) ? bsum[tid] : 0; ps[tid] = v; }
  __syncthreads();
  for (int off = 1; off < 128; off <<= 1) {
    int t = 0;
    if (tid < 128 && tid >= off) t = ps[tid - off];
    __syncthreads();
    if (tid < 128) ps[tid] += t;
    __syncthreads();
  }
  if (tid < 128) ps[tid] -= v;
  __syncthreads();
  for (int g = tid; g < NN; g += 512) rowptr[g] += ps[g >> 9];
  if (tid == 0) rowptr[NN] = EE;
}
__global__ void k_fill(const int* src, const int* dst, const int* rowptr, int* cnt, int* col) {
  int e = blockIdx.x * blockDim.x + threadIdx.x;
  if (e < EE) {
    int d = dst[e];
    int pos = rowptr[d] + atomicAdd(&cnt[d], 1);
    col[pos] = src[e];
  }
}

// ---------------- L1: fused assemble + x@W1 + coef ----------------
__global__ __launch_bounds__(256) void k_xl1(
    const void* vn_prefix, const int* vn_colors, const void* emb, const void* fn_embed,
    const void* msg_prefix, const float* hidcat, const void* W1, const void* a1s,
    const void* a1d, float* xl, float* a_s, float* a_d, const int* flg) {
  int f = flg[0];
  __shared__ float Wl[64 * 32];
  __shared__ float X[8][64];
  int tid = threadIdx.x;
  for (int t = tid; t < 2048; t += 256) Wl[t] = LD(W1, t, f);
  for (int t = tid; t < 512; t += 256) {
    int r = t >> 6, c = t & 63;
    int i = blockIdx.x * 8 + r;
    float v;
    if (i < NV) {
      v = (c < PFX) ? LD(vn_prefix, i * PFX + c, f) : LD(emb, vn_colors[i] * EMB + (c - PFX), f);
    } else if (i < NV + NF) {
      v = LD(fn_embed, (size_t)(i - NV) * 64 + c, f);
    } else {
      int jj = i - NV - NF;
      v = (c < PFX) ? LD(msg_prefix, jj * PFX + c, f) : hidcat[jj * EMB + (c - PFX)];
    }
    X[r][c] = v;
  }
  __syncthreads();
  int j = tid & 31, r = tid >> 5;
  int i = blockIdx.x * 8 + r;
  float acc = 0.f;
#pragma unroll
  for (int k = 0; k < 64; ++k) acc += X[r][k] * Wl[k * 32 + j];
  xl[(size_t)i * 32 + j] = acc;
  float sw = LD(a1s, j, f), dw = LD(a1d, j, f);
  float p = acc * sw, q = acc * dw;
#pragma unroll
  for (int off = 1; off < 8; off <<= 1) {
    p += __shfl_xor(p, off);
    q += __shfl_xor(q, off);
  }
  if ((j & 7) == 0) {
    a_s[(size_t)i * 4 + (j >> 3)] = p;
    a_d[(size_t)i * 4 + (j >> 3)] = q;
  }
}

// ---------------- GAT gather (max-free softmax, ECAP=32): MODE0/MODE1 ----------------
template <int MODE>
__global__ __launch_bounds__(256) void k_gather13(
    const int* rowptr, const int* col, const float* a_s, const float* a_d,
    const float* xl, const void* bias,
    const void* Wn, const void* asn_, const void* adn_,      // MODE0
    const float* waS, const float* waD,                       // MODE1
    float* xl_next, float* xout, float* as_out, float* ad_out, const int* flg) {
  int f = flg[0];
  __shared__ int colb[16][ECAP];
  __shared__ float4 eb[16][ECAP];
  __shared__ float Wn_l[32 * 32];
  __shared__ float an_s[32], an_d[32];
  __shared__ float Xr[16][33];
  __shared__ float SwaS[128], SwaD[128];
  int tid = threadIdx.x;
  if (MODE == 0) {
    for (int t = tid; t < 1024; t += 256) Wn_l[t] = LD(Wn, t, f);
    if (tid < 32) { an_s[tid] = LD(asn_, tid, f); an_d[tid] = LD(adn_, tid, f); }
  } else {
    if (tid < 128) { SwaS[tid] = waS[tid]; SwaD[tid] = waD[tid]; }
  }
  int g = tid >> 4, l = tid & 15;
  int i = blockIdx.x * 16 + g;
  int beg = rowptr[i], end = rowptr[i + 1];
  int deg = end - beg;
  float4 adv = *(const float4*)(a_d + (size_t)i * 4);
  float4 asv = *(const float4*)(a_s + (size_t)i * 4);
  float ad[4] = {adv.x, adv.y, adv.z, adv.w};
  float exS[4];
  {
    float asl[4] = {asv.x, asv.y, asv.z, asv.w};
#pragma unroll
    for (int h = 0; h < 4; ++h) exS[h] = fexp(lrelu(asl[h] + ad[h], 0.2f));
  }
  float den[4] = {0.f, 0.f, 0.f, 0.f};
  int c0 = l, c1 = l + 16;
  int h0 = l >> 3, h1 = 2 + (l >> 3);
  float acc0, acc1;

  if (deg <= ECAP) {
    for (int s = l; s < deg; s += 16) {
      int j = col[beg + s];
      colb[g][s] = j;
      float4 aj = *(const float4*)(a_s + (size_t)j * 4);
      float x0 = fexp(lrelu(aj.x + ad[0], 0.2f));
      float x1 = fexp(lrelu(aj.y + ad[1], 0.2f));
      float x2 = fexp(lrelu(aj.z + ad[2], 0.2f));
      float x3 = fexp(lrelu(aj.w + ad[3], 0.2f));
      eb[g][s] = make_float4(x0, x1, x2, x3);
      den[0] += x0; den[1] += x1; den[2] += x2; den[3] += x3;
    }
#pragma unroll
    for (int off = 1; off < 16; off <<= 1)
#pragma unroll
      for (int h = 0; h < 4; ++h) den[h] += __shfl_xor(den[h], off);
#pragma unroll
    for (int h = 0; h < 4; ++h) den[h] += exS[h];
    acc0 = exS[h0] * xl[(size_t)i * 32 + c0];
    acc1 = exS[h1] * xl[(size_t)i * 32 + c1];
#pragma unroll 2
    for (int s = 0; s < deg; ++s) {
      int j = colb[g][s];
      float4 e4 = eb[g][s];
      float w0 = h0 ? e4.y : e4.x;
      float w1 = (l >> 3) ? e4.w : e4.z;
      acc0 += w0 * xl[(size_t)j * 32 + c0];
      acc1 += w1 * xl[(size_t)j * 32 + c1];
    }
  } else {
    for (int s = l; s < deg; s += 16) {
      int j = col[beg + s];
      float4 aj = *(const float4*)(a_s + (size_t)j * 4);
      den[0] += fexp(lrelu(aj.x + ad[0], 0.2f));
      den[1] += fexp(lrelu(aj.y + ad[1], 0.2f));
      den[2] += fexp(lrelu(aj.z + ad[2], 0.2f));
      den[3] += fexp(lrelu(aj.w + ad[3], 0.2f));
    }
#pragma unroll
    for (int off = 1; off < 16; off <<= 1)
#pragma unroll
      for (int h = 0; h < 4; ++h) den[h] += __shfl_xor(den[h], off);
#pragma unroll
    for (int h = 0; h < 4; ++h) den[h] += exS[h];
    acc0 = exS[h0] * xl[(size_t)i * 32 + c0];
    acc1 = exS[h1] * xl[(size_t)i * 32 + c1];
    for (int s = 0; s < deg; ++s) {
      int j = col[beg + s];
      float e0 = fexp(lrelu(a_s[(size_t)j * 4 + h0] + ad[h0], 0.2f));
      float e1 = fexp(lrelu(a_s[(size_t)j * 4 + h1] + ad[h1], 0.2f));
      acc0 += e0 * xl[(size_t)j * 32 + c0];
      acc1 += e1 * xl[(size_t)j * 32 + c1];
    }
  }
  float v0 = lrelu(acc0 / den[h0] + LD(bias, c0, f), 0.01f);
  float v1 = lrelu(acc1 / den[h1] + LD(bias, c1, f), 0.01f);

  if (MODE == 0) {
    Xr[g][c0] = v0;
    Xr[g][c1] = v1;
    __syncthreads();
    float n0 = 0.f, n1 = 0.f;
#pragma unroll
    for (int k = 0; k < 32; ++k) {
      float xv = Xr[g][k];
      n0 += xv * Wn_l[k * 32 + c0];
      n1 += xv * Wn_l[k * 32 + c1];
    }
    xl_next[(size_t)i * 32 + c0] = n0;
    xl_next[(size_t)i * 32 + c1] = n1;
    float p0 = n0 * an_s[c0], q0 = n0 * an_d[c0];
    float p1 = n1 * an_s[c1], q1 = n1 * an_d[c1];
#pragma unroll
    for (int off = 1; off < 8; off <<= 1) {
      p0 += __shfl_xor(p0, off); q0 += __shfl_xor(q0, off);
      p1 += __shfl_xor(p1, off); q1 += __shfl_xor(q1, off);
    }
    if ((l & 7) == 0) {
      as_out[(size_t)i * 4 + h0] = p0;
      ad_out[(size_t)i * 4 + h0] = q0;
      as_out[(size_t)i * 4 + h1] = p1;
      ad_out[(size_t)i * 4 + h1] = q1;
    }
  } else {
    xout[(size_t)i * 32 + c0] = v0;
    xout[(size_t)i * 32 + c1] = v1;
    float pS[4], pD[4];
#pragma unroll
    for (int h = 0; h < 4; ++h) {
      pS[h] = v0 * SwaS[h * 32 + c0] + v1 * SwaS[h * 32 + c1];
      pD[h] = v0 * SwaD[h * 32 + c0] + v1 * SwaD[h * 32 + c1];
    }
#pragma unroll
    for (int off = 1; off < 16; off <<= 1)
#pragma unroll
      for (int h = 0; h < 4; ++h) { pS[h] += __shfl_xor(pS[h], off); pD[h] += __shfl_xor(pD[h], off); }
    if (l == 0) {
#pragma unroll
      for (int h = 0; h < 4; ++h) {
        as_out[(size_t)i * 4 + h] = pS[h];
        ad_out[(size_t)i * 4 + h] = pD[h];
      }
    }
  }
}

// ---------------- L4 fused: gather4 + 128->64 GEMM + qk, 16 fn-rows/block ----------------
__global__ __launch_bounds__(256) void k_l4fused(
    const int* rowptr, const int* col, const float* a_s, const float* a_d,
    const float* x, const void* W4, const void* b4,
    const float* wqv, const float* wkv, float* qs, float* ks, const int* flg) {
  int f = flg[0];
  __shared__ int colb[16][ECAP];
  __shared__ float4 eb[16][ECAP];
  __shared__ float Aq[16][132];     // agg rows, padded
  __shared__ float Wl[128 * 64];    // W'[K][c]
  __shared__ float Ql[256], Kl[256];
  int tid = threadIdx.x;
  // issue weight staging first (latency hides under gather)
  for (int t = tid; t < 128 * 64; t += 256) {
    int K = t >> 6, c = t & 63;
    int h = K >> 5, k = K & 31;
    Wl[t] = LD(W4, k * 256 + h * 64 + c, f);
  }
  if (tid < 256) { Ql[tid] = wqv[tid]; Kl[tid] = wkv[tid]; }

  int g = tid >> 4, l = tid & 15;
  int i = NV + blockIdx.x * 16 + g;
  int beg = rowptr[i], end = rowptr[i + 1];
  int deg = end - beg;
  float4 adv = *(const float4*)(a_d + (size_t)i * 4);
  float4 asv = *(const float4*)(a_s + (size_t)i * 4);
  float ad[4] = {adv.x, adv.y, adv.z, adv.w};
  float exS[4];
  {
    float asl[4] = {asv.x, asv.y, asv.z, asv.w};
#pragma unroll
    for (int h = 0; h < 4; ++h) exS[h] = fexp(lrelu(asl[h] + ad[h], 0.2f));
  }
  float den[4] = {0.f, 0.f, 0.f, 0.f};
  int k0 = l, k1 = l + 16;
  float acc[4][2];

  if (deg <= ECAP) {
    for (int s = l; s < deg; s += 16) {
      int j = col[beg + s];
      colb[g][s] = j;
      float4 aj = *(const float4*)(a_s + (size_t)j * 4);
      float x0 = fexp(lrelu(aj.x + ad[0], 0.2f));
      float x1 = fexp(lrelu(aj.y + ad[1], 0.2f));
      float x2 = fexp(lrelu(aj.z + ad[2], 0.2f));
      float x3 = fexp(lrelu(aj.w + ad[3], 0.2f));
      eb[g][s] = make_float4(x0, x1, x2, x3);
      den[0] += x0; den[1] += x1; den[2] += x2; den[3] += x3;
    }
#pragma unroll
    for (int off = 1; off < 16; off <<= 1)
#pragma unroll
      for (int h = 0; h < 4; ++h) den[h] += __shfl_xor(den[h], off);
    float xs0 = x[(size_t)i * 32 + k0], xs1 = x[(size_t)i * 32 + k1];
#pragma unroll
    for (int h = 0; h < 4; ++h) {
      den[h] += exS[h];
      acc[h][0] = exS[h] * xs0;
      acc[h][1] = exS[h] * xs1;
    }
#pragma unroll 2
    for (int s = 0; s < deg; ++s) {
      int j = colb[g][s];
      float4 e4 = eb[g][s];
      float xv0 = x[(size_t)j * 32 + k0], xv1 = x[(size_t)j * 32 + k1];
      acc[0][0] += e4.x * xv0; acc[0][1] += e4.x * xv1;
      acc[1][0] += e4.y * xv0; acc[1][1] += e4.y * xv1;
      acc[2][0] += e4.z * xv0; acc[2][1] += e4.z * xv1;
      acc[3][0] += e4.w * xv0; acc[3][1] += e4.w * xv1;
    }
  } else {
    for (int s = l; s < deg; s += 16) {
      int j = col[beg + s];
      float4 aj = *(const float4*)(a_s + (size_t)j * 4);
      den[0] += fexp(lrelu(aj.x + ad[0], 0.2f));
      den[1] += fexp(lrelu(aj.y + ad[1], 0.2f));
      den[2] += fexp(lrelu(aj.z + ad[2], 0.2f));
      den[3] += fexp(lrelu(aj.w + ad[3], 0.2f));
    }
#pragma unroll
    for (int off = 1; off < 16; off <<= 1)
#pragma unroll
      for (int h = 0; h < 4; ++h) den[h] += __shfl_xor(den[h], off);
    float xs0 = x[(size_t)i * 32 + k0], xs1 = x[(size_t)i * 32 + k1];
#pragma unroll
    for (int h = 0; h < 4; ++h) {
      den[h] += exS[h];
      acc[h][0] = exS[h] * xs0;
      acc[h][1] = exS[h] * xs1;
    }
    for (int s = 0; s < deg; ++s) {
      int j = col[beg + s];
      float4 aj = *(const float4*)(a_s + (size_t)j * 4);
      float e0 = fexp(lrelu(aj.x + ad[0], 0.2f));
      float e1 = fexp(lrelu(aj.y + ad[1], 0.2f));
      float e2 = fexp(lrelu(aj.z + ad[2], 0.2f));
      float e3 = fexp(lrelu(aj.w + ad[3], 0.2f));
      float xv0 = x[(size_t)j * 32 + k0], xv1 = x[(size_t)j * 32 + k1];
      acc[0][0] += e0 * xv0; acc[0][1] += e0 * xv1;
      acc[1][0] += e1 * xv0; acc[1][1] += e1 * xv1;
      acc[2][0] += e2 * xv0; acc[2][1] += e2 * xv1;
      acc[3][0] += e3 * xv0; acc[3][1] += e3 * xv1;
    }
  }
#pragma unroll
  for (int h = 0; h < 4; ++h) {
    Aq[g][h * 32 + k0] = acc[h][0] / den[h];
    Aq[g][h * 32 + k1] = acc[h][1] / den[h];
  }
  __syncthreads();

  // phase 2: out[r, c0..c0+3] = lrelu(0.25 * sum_K Aq[r][K]*Wl[K][c] + b4), then qk
  int r = tid >> 4, c0 = (tid & 15) << 2;
  float o4[4] = {0.f, 0.f, 0.f, 0.f};
#pragma unroll 4
  for (int K = 0; K < 128; ++K) {
    float a = Aq[r][K];
    float4 wv = *(const float4*)&Wl[K * 64 + c0];
    o4[0] += a * wv.x; o4[1] += a * wv.y; o4[2] += a * wv.z; o4[3] += a * wv.w;
  }
#pragma unroll
  for (int c = 0; c < 4; ++c)
    o4[c] = lrelu(0.25f * o4[c] + LD(b4, c0 + c, f), 0.01f);
  int n = NV + blockIdx.x * 16 + r - NV;  // fn-row index
  n = blockIdx.x * 16 + r;
#pragma unroll
  for (int h = 0; h < 4; ++h) {
    float pq = o4[0] * Ql[h * 64 + c0] + o4[1] * Ql[h * 64 + c0 + 1] +
               o4[2] * Ql[h * 64 + c0 + 2] + o4[3] * Ql[h * 64 + c0 + 3];
    float pk = o4[0] * Kl[h * 64 + c0] + o4[1] * Kl[h * 64 + c0 + 1] +
               o4[2] * Kl[h * 64 + c0 + 2] + o4[3] * Kl[h * 64 + c0 + 3];
#pragma unroll
    for (int off = 1; off < 16; off <<= 1) {
      pq += __shfl_xor(pq, off);
      pk += __shfl_xor(pk, off);
    }
    if ((tid & 15) == 0) {
      qs[(size_t)n * 4 + h] = pq;
      ks[(size_t)n * 4 + h] = pk;
    }
  }
}

__global__ void k_groups(const int* full, const void* mask, const int* tgt, const int* mult,
                         const float* qs, const float* ks, const void* att_b, void* outv,
                         const int* flg) {
  int f = flg[0], mbyte = flg[1];
  int g = blockIdx.x;
  int lane = threadIdx.x;
  int k = lane >> 2, h = lane & 3;
  int t = tgt[g];
  int idx = full[g * KK + k];
  int mk = MK(mask, g * KK + k, mbyte);
  float bh = LD(att_b, h, f);
  float qt = qs[t * 4 + h];
  float sc = sigm(qt + ks[idx * 4 + h] + bh);
  int is_tgt = (idx == t) && mk;
  int nbr = mk && !is_tgt;
  unsigned long long bal = __ballot(nbr != 0);
  int degm1 = (int)(__popcll(bal) >> 2);
  float ssum = nbr ? sc : 0.f;
  for (int off = 4; off < 64; off <<= 1) ssum += __shfl_xor(ssum, off);
  ssum /= (float)(degm1 > 1 ? degm1 : 1);
  float trg = sigm(qt + ks[t * 4 + h] + bh);
  float mxv = fmaxf(ssum, trg);
  float e0 = expf(ssum - mxv), e1 = expf(trg - mxv);
  float tw0 = e0 / (e0 + e1), tw1 = e1 / (e0 + e1);
  float msc = nbr ? sc : -1e30f;
  float m = msc;
  for (int off = 4; off < 64; off <<= 1) m = fmaxf(m, __shfl_xor(m, off));
  float ex = expf(msc - m);
  float den = ex;
  for (int off = 4; off < 64; off <<= 1) den += __shfl_xor(den, off);
  float w = ex / den * tw0 * (float)mult[g];
  float res = is_tgt ? tw1 : (nbr ? w : 0.f);
  if (degm1 == 0) res = 0.f;
  ST(outv, g * 64 + k * 4 + h, f, res);
}

extern "C" void kernel_launch(void* const* d_in, const int* in_sizes, int n_in,
                              void* d_out, int out_size, void* d_ws, size_t ws_size,
                              hipStream_t stream) {
  const int* edge = (const int*)d_in[0];
  const int* esrc = edge;
  const int* edst = edge + EE;
  const int* vn_colors = (const int*)d_in[1];
  const int* group_full = (const int*)d_in[2];
  const void* group_mask = d_in[3];
  const int* group_tgt = (const int*)d_in[4];
  const int* group_mult = (const int*)d_in[5];
  const void* vn_prefix = d_in[6];
  const void* fn_embed = d_in[7];
  const void* v2f_msgs = d_in[8];
  const void* v2f_hidden = d_in[9];
  const void* f2v_msgs = d_in[10];
  const void* f2v_hidden = d_in[11];
  const void* msg_prefix = d_in[12];
  const void* emb = d_in[13];
  const void* gv_wih = d_in[14];
  const void* gv_whh = d_in[15];
  const void* gv_bih = d_in[16];
  const void* gv_bhh = d_in[17];
  const void* gf_wih = d_in[18];
  const void* gf_whh = d_in[19];
  const void* gf_bih = d_in[20];
  const void* gf_bhh = d_in[21];
  const void* W1 = d_in[22];
  const void* a1s = d_in[23];
  const void* a1d = d_in[24];
  const void* b1 = d_in[25];
  const void* W2 = d_in[26];
  const void* a2s = d_in[27];
  const void* a2d = d_in[28];
  const void* b2 = d_in[29];
  const void* W3 = d_in[30];
  const void* a3s = d_in[31];
  const void* a3d = d_in[32];
  const void* b3 = d_in[33];
  const void* W4 = d_in[34];
  const void* a4s = d_in[35];
  const void* a4d = d_in[36];
  const void* b4 = d_in[37];
  const void* att_wq = d_in[38];
  const void* att_wk = d_in[39];
  const void* att_ws = d_in[40];
  const void* att_b = d_in[41];

  char* w = (char*)d_ws;
  size_t off = 0;
  auto carve = [&](size_t bytes) -> void* {
    void* p = w + off;
    off += (bytes + 255) & ~(size_t)255;
    return p;
  };
  int* flags = (int*)carve(16);
  float* Wt = (float*)carve((size_t)2 * 77 * 192 * 4);
  float* hidcat = (float*)carve((size_t)2 * NM * EMB * 4);
  float* xB = (float*)carve((size_t)NN * 64 * 4);
  float* scr = (float*)carve((size_t)NN * 128 * 4);
  float* a_sA = (float*)carve((size_t)NN * 4 * 4);
  float* a_dA = (float*)carve((size_t)NN * 4 * 4);
  float* a_sB = (float*)carve((size_t)NN * 4 * 4);
  float* a_dB = (float*)carve((size_t)NN * 4 * 4);
  int* deg = (int*)carve((size_t)2 * NN * 4);  // deg + cnt adjacent, zeroed in k_precomp
  int* cnt = deg + NN;
  int* rowptr = (int*)carve((size_t)(NN + 1) * 4);
  int* bsum = (int*)carve(128 * 4);
  int* col = (int*)carve((size_t)EE * 4);
  float* qs = (float*)carve((size_t)NF * 4 * 4);
  float* ks = (float*)carve((size_t)NF * 4 * 4);
  float* wqv = (float*)carve(256 * 4);
  float* wkv = (float*)carve(256 * 4);
  float* waS = (float*)carve(128 * 4);
  float* waD = (float*)carve(128 * 4);

  k_precomp<<<118 + (2 * NN + 255) / 256, 256, 0, stream>>>(
      gv_wih, gv_whh, gf_wih, gf_whh, W4, a4s, a4d,
      att_wq, att_wk, att_ws, fn_embed, group_mask,
      Wt, waS, waD, wqv, wkv, deg, flags);
  k_gru2<<<768, 256, 0, stream>>>(v2f_msgs, v2f_hidden, f2v_msgs, f2v_hidden,
                                  gv_bih, gv_bhh, gf_bih, gf_bhh, Wt, hidcat, d_out, flags);
  k_deg<<<EE / 256, 256, 0, stream>>>(edst, deg);
  k_scan1<<<72, 512, 0, stream>>>(deg, rowptr, bsum);
  k_scan23<<<1, 512, 0, stream>>>(rowptr, bsum, 72);
  k_fill<<<EE / 256, 256, 0, stream>>>(esrc, edst, rowptr, cnt, col);

  // L1: assemble + x@W1 + coef1 -> xl1 in scr, coefs in A
  k_xl1<<<NN / 8, 256, 0, stream>>>(vn_prefix, vn_colors, emb, fn_embed, msg_prefix,
                                    hidcat, W1, a1s, a1d, scr, a_sA, a_dA, flags);
  // gather L1 (+xl2+coef2): scr,A -> xB,B
  k_gather13<0><<<NN / 16, 256, 0, stream>>>(rowptr, col, a_sA, a_dA, scr, b1,
                                             W2, a2s, a2d, nullptr, nullptr,
                                             xB, nullptr, a_sB, a_dB, flags);
  // gather L2 (+xl3+coef3): xB,B -> scr,A
  k_gather13<0><<<NN / 16, 256, 0, stream>>>(rowptr, col, a_sB, a_dB, xB, b2,
                                             W3, a3s, a3d, nullptr, nullptr,
                                             scr, nullptr, a_sA, a_dA, flags);
  // gather L3 (+act out + coef4): scr,A -> xB (act), B (coef4)
  k_gather13<1><<<NN / 16, 256, 0, stream>>>(rowptr, col, a_sA, a_dA, scr, b3,
                                             nullptr, nullptr, nullptr, waS, waD,
                                             nullptr, xB, a_sB, a_dB, flags);
  // L4 fused (fn rows only): gather + GEMM + qk
  k_l4fused<<<NF / 16, 256, 0, stream>>>(rowptr, col, a_sB, a_dB, xB, W4, b4,
                                         wqv, wkv, qs, ks, flags);

  k_groups<<<GG, 64, 0, stream>>>(group_full, group_mask, group_tgt, group_mult,
                                  qs, ks, att_b, d_out, flags);
}